// Round 18
// baseline (1749.928 us; speedup 1.0000x reference)
//
#include <hip/hip_runtime.h>
#include <cstdint>
#include <cstddef>

#define NN 500
#define KP 512   // node dim padded to 512 for f16 MFMA operands

typedef _Float16 f16;
typedef _Float16 half8 __attribute__((ext_vector_type(8)));
typedef float floatx4 __attribute__((ext_vector_type(4)));

// 10 flattened GEMM passes: acc += A[p] * B[p]^T.
struct PassSet {
  const f16* A[10];
  const f16* B[10];
};

// ---------------------------------------------------------------------------
// adp = softmax(relu(E1 @ E2), axis=1)
__global__ __launch_bounds__(256) void adp_kernel(const float* __restrict__ e1,
                                                  const float* __restrict__ e2,
                                                  float* __restrict__ adp) {
  int r = blockIdx.x;
  int tid = threadIdx.x;
  __shared__ float red[256];
  __shared__ float e1row[16];
  if (tid < 10) e1row[tid] = e1[r * 10 + tid];
  __syncthreads();
  float z0, z1 = 0.f;
  {
    float acc = 0.f;
#pragma unroll
    for (int k = 0; k < 10; k++) acc += e1row[k] * e2[k * NN + tid];
    z0 = fmaxf(acc, 0.f);
  }
  bool has1 = (tid + 256) < NN;
  if (has1) {
    float acc = 0.f;
#pragma unroll
    for (int k = 0; k < 10; k++) acc += e1row[k] * e2[k * NN + tid + 256];
    z1 = fmaxf(acc, 0.f);
  }
  float mx = has1 ? fmaxf(z0, z1) : z0;
  red[tid] = mx;
  __syncthreads();
  for (int s = 128; s > 0; s >>= 1) {
    if (tid < s) red[tid] = fmaxf(red[tid], red[tid + s]);
    __syncthreads();
  }
  mx = red[0];
  __syncthreads();
  float ex0 = __expf(z0 - mx);
  float ex1 = has1 ? __expf(z1 - mx) : 0.f;
  red[tid] = ex0 + ex1;
  __syncthreads();
  for (int s = 128; s > 0; s >>= 1) {
    if (tid < s) red[tid] += red[tid + s];
    __syncthreads();
  }
  float inv = 1.f / red[0];
  adp[r * NN + tid] = ex0 * inv;
  if (has1) adp[r * NN + tid + 256] = ex1 * inv;
}

// ---------------------------------------------------------------------------
// xT[bc][t][n] = x[bc][n][t]  (coalesced reads for the fused layer-0 dconv)
__global__ __launch_bounds__(256) void xt_kernel(const float* __restrict__ x,
                                                 float* __restrict__ xT) {
  __shared__ float tile[32][33];
  int tx = threadIdx.x & 31, ty = threadIdx.x >> 5;
  int n0 = blockIdx.x * 32, t0 = blockIdx.y * 32, bc = blockIdx.z;
#pragma unroll
  for (int rr = 0; rr < 4; rr++) {
    int n = n0 + ty + rr * 8, t = t0 + tx;
    tile[ty + rr * 8][tx] = (n < NN) ? x[((size_t)bc * NN + n) * 256 + t] : 0.f;
  }
  __syncthreads();
#pragma unroll
  for (int rr = 0; rr < 4; rr++) {
    int t = t0 + ty + rr * 8, n = n0 + tx;
    if (n < NN) xT[((size_t)bc * 256 + t) * NN + n] = tile[tx][ty + rr * 8];
  }
}

// ---------------------------------------------------------------------------
// Transpose dconv weights [i][c][cp][tap] -> [i][cp][tap][c] (contiguous runs).
__global__ __launch_bounds__(256) void wtr_kernel(const float* __restrict__ fw,
                                                  const float* __restrict__ gw,
                                                  float* __restrict__ fwT,
                                                  float* __restrict__ gwT) {
  int idx = blockIdx.x * 256 + threadIdx.x;  // 8*32*32*2 = 16384
  if (idx >= 16384) return;
  int c = idx & 31;
  int rest = idx >> 5;   // (i*32+cp)*2+tap
  int tap = rest & 1;
  int cpi = rest >> 1;   // i*32+cp
  int cp = cpi & 31, i = cpi >> 5;
  size_t src = (((size_t)(i * 32 + c) * 32 + cp) * 2) + tap;
  fwT[idx] = fw[src];
  gwT[idx] = gw[src];
}

// ---------------------------------------------------------------------------
// B^T as f16 hi/lo pair: hi[w][v]+lo[w][v] ~= src[v][w], 512x512 zero-padded.
__global__ __launch_bounds__(256) void bt_kernel(const float* __restrict__ src,
                                                 f16* __restrict__ hi,
                                                 f16* __restrict__ lo) {
  int idx = blockIdx.x * 256 + threadIdx.x;  // 512*512 total
  int w = idx >> 9, v = idx & 511;
  float x = (w < NN && v < NN) ? src[v * NN + w] : 0.f;
  f16 h = (f16)x;
  hi[idx] = h;
  lo[idx] = (f16)(x - (float)h);
}

// ---------------------------------------------------------------------------
// Squared-matrix B^T pair: dst[w][v] = (src @ src)[v][w].
__global__ __launch_bounds__(512) void sq_kernel(const float* __restrict__ srcA,
                                                 const float* __restrict__ srcB,
                                                 f16* __restrict__ hiA, f16* __restrict__ loA,
                                                 f16* __restrict__ hiB, f16* __restrict__ loB) {
  const float* src = blockIdx.y == 0 ? srcA : srcB;
  f16* hi = blockIdx.y == 0 ? hiA : hiB;
  f16* lo = blockIdx.y == 0 ? loA : loB;
  int v = blockIdx.x;   // 0..511
  int w = threadIdx.x;  // 0..511
  __shared__ float vrow[512];
  vrow[w] = (v < NN && w < NN) ? src[v * NN + w] : 0.f;
  __syncthreads();
  float acc = 0.f;
  if (v < NN && w < NN) {
#pragma unroll 4
    for (int u = 0; u < NN; u++) acc = fmaf(vrow[u], src[u * NN + w], acc);
  }
  size_t o = (size_t)w * 512 + v;
  f16 h = (f16)acc;
  hi[o] = h;
  lo[o] = (f16)(acc - (float)h);
}

// ---------------------------------------------------------------------------
// Zero pad columns [500,512) of the six f16 P arrays (ws re-poisoned 0xAA).
__global__ __launch_bounds__(256) void padzero_kernel(uint32_t* __restrict__ slab, int R) {
  int idx = blockIdx.x * 256 + threadIdx.x;
  int total = 6 * R * 6;
  if (idx >= total) return;
  int a = idx / (R * 6);
  int rem = idx - a * R * 6;
  int row = rem / 6;
  int q = rem - row * 6;
  slab[(size_t)a * R * 256 + (size_t)row * 256 + 250 + q] = 0u;
}

// ---------------------------------------------------------------------------
// Fused (start-conv) + dilated-conv + gating + GCN channel-mix.
// ROUND 29 (kept): launch_bounds (256,2) freed the acc arrays from AGPR
// round-trips (total -114us). h residual stream fp32 (f16 failed r8).
// fw/gw TRANSPOSED [cp][tap][c]. All register-array index loops fully
// unrolled (r1). Grid: (j, bb, nhalf).
template <bool FUSED>
__global__ __launch_bounds__(256, 2) void dcm_kernel(
    const float* __restrict__ hprev, const float* __restrict__ xT,
    const float* __restrict__ sw, const float* __restrict__ sb,
    const float* __restrict__ fw, const float* __restrict__ fb,
    const float* __restrict__ gw, const float* __restrict__ gb,
    const float* __restrict__ cw, const float* __restrict__ cb,
    float* __restrict__ Hout,
    f16* __restrict__ P1a,
    f16* __restrict__ P2aH, f16* __restrict__ P2aL,
    f16* __restrict__ P1b,
    f16* __restrict__ P2bH, f16* __restrict__ P2bL,
    float* __restrict__ tapL,
    int Lp, int L, int b0) {
  int j = blockIdx.x, bb = blockIdx.y;
  int n0 = blockIdx.z * 256 + threadIdx.x;
  bool ok = (n0 < NN);
  int nc = ok ? n0 : (NN - 1);  // clamped index for always-valid loads
  size_t base = ((size_t)(bb * 32) * Lp + 2 * j) * NN;
  size_t cs = (size_t)Lp * NN;
  float x00 = 0.f, x01 = 0.f, x10 = 0.f, x11 = 0.f;
  if (FUSED) {
    const float* xb = xT + (size_t)(b0 + bb) * 2 * 256 * NN;
    x00 = xb[(size_t)(2 * j) * NN + nc];
    x01 = xb[(size_t)(2 * j + 1) * NN + nc];
    x10 = xb[(size_t)(256 + 2 * j) * NN + nc];
    x11 = xb[(size_t)(256 + 2 * j + 1) * NN + nc];
  }
  float accf[32], accg[32];
#pragma unroll
  for (int c = 0; c < 32; c++) {
    accf[c] = fb[c];
    accg[c] = gb[c];
  }
#pragma unroll 2
  for (int cp = 0; cp < 32; cp++) {
    float v0, v1;
    if (FUSED) {
      float w0 = sw[cp * 2], w1 = sw[cp * 2 + 1], bc = sb[cp];
      v0 = fmaf(w0, x00, fmaf(w1, x10, bc));
      v1 = fmaf(w0, x01, fmaf(w1, x11, bc));
    } else {
      const float* hp = hprev + base + cp * cs;
      v0 = hp[nc];
      v1 = hp[NN + nc];
    }
    const float* fwp = fw + cp * 64;  // [cp][tap][c]: 64 contiguous floats
    const float* gwp = gw + cp * 64;
#pragma unroll
    for (int c = 0; c < 32; c++) {
      float fw0 = fwp[c], fw1 = fwp[32 + c];
      float gw0 = gwp[c], gw1 = gwp[32 + c];
      accf[c] = fmaf(fw0, v0, accf[c]);
      accf[c] = fmaf(fw1, v1, accf[c]);
      accg[c] = fmaf(gw0, v0, accg[c]);
      accg[c] = fmaf(gw1, v1, accg[c]);
    }
  }
  float FG[32];
#pragma unroll
  for (int c = 0; c < 32; c++) {
    float E0 = __expf(2.f * accf[c]);
    float th0 = 1.f - 2.f / (E0 + 1.f);
    float sg0 = 1.f / (1.f + __expf(-accg[c]));
    FG[c] = th0 * sg0;
  }
  if (j == L - 1 && ok) {
    size_t tbase = ((size_t)(b0 + bb) * 32) * NN;
#pragma unroll
    for (int c = 0; c < 32; c++) {
      tapL[tbase + (size_t)c * NN + n0] = FG[c];
    }
  }
  if (Hout == nullptr) return;  // layer 8: only the skip tap survives
#pragma unroll 2
  for (int c = 0; c < 32; c++) {
    const float* wr = cw + c * 160;
    float cbc = cb[c];
    float h0 = cbc, p10 = 0.f, p20 = 0.f, q10 = 0.f, q20 = 0.f;
#pragma unroll
    for (int cp = 0; cp < 32; cp++) {
      float w0 = wr[cp], w1 = wr[32 + cp], w2 = wr[64 + cp];
      float w3 = wr[96 + cp], w4 = wr[128 + cp];
      float f0 = FG[cp];
      h0  = fmaf(w0, f0, h0);
      p10 = fmaf(w1, f0, p10);
      p20 = fmaf(w2, f0, p20);
      q10 = fmaf(w3, f0, q10);
      q20 = fmaf(w4, f0, q20);
    }
    // residual = hprev[2j+1] (start-conv output for layer 0)
    if (FUSED) {
      float sw0 = sw[c * 2], sw1 = sw[c * 2 + 1], sbc = sb[c];
      h0 += fmaf(sw0, x01, fmaf(sw1, x11, sbc));
    } else {
      const float* hr = hprev + ((size_t)(bb * 32 + c) * Lp + 2 * j + 1) * NN;
      h0 += hr[nc];
    }
    if (ok) {
      size_t mi = (size_t)(bb * 32 + c) * L + j;
      size_t o = mi * KP;
      f16 t;
      Hout[mi * NN + n0] = h0;
      P1a[o + n0] = (f16)p10;
      t = (f16)p20; P2aH[o + n0] = t; P2aL[o + n0] = (f16)(p20 - (float)t);
      P1b[o + n0] = (f16)q10;
      t = (f16)q20; P2bH[o + n0] = t; P2bL[o + n0] = (f16)(q20 - (float)t);
    }
  }
}

// ---------------------------------------------------------------------------
// ROUND 28 mfma_gcn (128x64, 4096<M<8192 fallback): BK=64, named scalar
// prefetch, separate As0/As1/Bs0/Bs1 LDS (24KB), launch_bounds(256,3).
// VERIFIED r28 (no spill). Unchanged.
__global__ __launch_bounds__(256, 3) void mfma_gcn(PassSet s,
    const float* __restrict__ Cin, float* __restrict__ Out, int M,
    const float* __restrict__ bng, const float* __restrict__ bnb, int lshift) {
  __shared__ f16 As0[128 * 32];
  __shared__ f16 As1[128 * 32];
  __shared__ f16 Bs0[64 * 32];
  __shared__ f16 Bs1[64 * 32];
  int tid = threadIdx.x;
  int wave = tid >> 6, lane = tid & 63;
  int wm = wave >> 1, wn = wave & 1;
  int m0 = blockIdx.x * 128;
  int n0 = blockIdx.y * 64;
  int lm = lane & 15, kq = lane >> 4;  // frag: row lm, k-quad kq (8 k)
  // staging: A rows (tid>>2) and (tid>>2)+64 (16B chunk tid&3); B row (tid>>2)
  int srow = tid >> 2, sc = tid & 3;
  int ar0 = m0 + srow;      if (ar0 > M - 1) ar0 = M - 1;
  int ar1 = m0 + srow + 64; if (ar1 > M - 1) ar1 = M - 1;
  size_t ag0 = (size_t)ar0 * KP + sc * 8;
  size_t ag1 = (size_t)ar1 * KP + sc * 8;
  size_t bg0 = (size_t)(n0 + srow) * KP + sc * 8;  // rows n0..n0+63 (<512 pad)
  // XOR-swizzled LDS offsets (f16 units): off = row*32 + (chunk^((row>>1)&3))*8
  int sl0 = srow * 32 + ((sc ^ ((srow >> 1) & 3)) << 3);
  int sl1 = sl0 + 64 * 32;  // A second half
  // fragment reads: row = base16 + lm (base16 multiple of 16) -> key (lm>>1)&3
  int ach = kq ^ ((lm >> 1) & 3);

  floatx4 acc[4][2];
#pragma unroll
  for (int i = 0; i < 4; i++)
#pragma unroll
    for (int j = 0; j < 2; j++) acc[i][j] = (floatx4){0.f, 0.f, 0.f, 0.f};

  // named scalars: X = row-block (0: srow, 1: srow+64), suffix x/y = sub-strip
  float4 pa0x, pa0y, pa1x, pa1y, pb0x, pb0y;
  {
    const f16* Ap = s.A[0];
    const f16* Bp = s.B[0];
    pa0x = *(const float4*)(Ap + ag0);
    pa0y = *(const float4*)(Ap + ag0 + 32);
    pa1x = *(const float4*)(Ap + ag1);
    pa1y = *(const float4*)(Ap + ag1 + 32);
    pb0x = *(const float4*)(Bp + bg0);
    pb0y = *(const float4*)(Bp + bg0 + 32);
  }
#pragma unroll
  for (int p = 0; p < 10; p++) {
    const f16* __restrict__ Ap = s.A[p];
    const f16* __restrict__ Bp = s.B[p];
    const f16* __restrict__ Apn = s.A[p < 9 ? p + 1 : p];
    const f16* __restrict__ Bpn = s.B[p < 9 ? p + 1 : p];
    for (int k0 = 0; k0 < KP; k0 += 64) {
      __syncthreads();  // prior compute done reading LDS
      *(float4*)(As0 + sl0) = pa0x;
      *(float4*)(As1 + sl0) = pa0y;
      *(float4*)(As0 + sl1) = pa1x;
      *(float4*)(As1 + sl1) = pa1y;
      *(float4*)(Bs0 + sl0) = pb0x;
      *(float4*)(Bs1 + sl0) = pb0y;
      __syncthreads();  // staging visible
      {  // prefetch next round (2 sub-strips); latency overlaps compute
        bool lastk = (k0 == KP - 64);
        const f16* An = lastk ? Apn : Ap;
        const f16* Bn = lastk ? Bpn : Bp;
        int kn = lastk ? 0 : k0 + 64;
        pa0x = *(const float4*)(An + ag0 + kn);
        pa0y = *(const float4*)(An + ag0 + kn + 32);
        pa1x = *(const float4*)(An + ag1 + kn);
        pa1y = *(const float4*)(An + ag1 + kn + 32);
        pb0x = *(const float4*)(Bn + bg0 + kn);
        pb0y = *(const float4*)(Bn + bg0 + kn + 32);
      }
      {  // sub-strip 0 (k0)
        half8 a[4];
#pragma unroll
        for (int i = 0; i < 4; i++)
          a[i] = *(const half8*)(As0 + (wm * 64 + i * 16 + lm) * 32 + ach * 8);
#pragma unroll
        for (int j = 0; j < 2; j++) {
          half8 b = *(const half8*)(Bs0 + (wn * 32 + j * 16 + lm) * 32 + ach * 8);
#pragma unroll
          for (int i = 0; i < 4; i++)
            acc[i][j] = __builtin_amdgcn_mfma_f32_16x16x32_f16(a[i], b, acc[i][j], 0, 0, 0);
        }
      }
      {  // sub-strip 1 (k0+32)
        half8 a[4];
#pragma unroll
        for (int i = 0; i < 4; i++)
          a[i] = *(const half8*)(As1 + (wm * 64 + i * 16 + lm) * 32 + ach * 8);
#pragma unroll
        for (int j = 0; j < 2; j++) {
          half8 b = *(const half8*)(Bs1 + (wn * 32 + j * 16 + lm) * 32 + ach * 8);
#pragma unroll
          for (int i = 0; i < 4; i++)
            acc[i][j] = __builtin_amdgcn_mfma_f32_16x16x32_f16(a[i], b, acc[i][j], 0, 0, 0);
        }
      }
    }
  }
  // epilogue: C/D layout col = lane&15, row = (lane>>4)*4 + reg
  int cn = lane & 15, rq = lane >> 4;
  float rs = rsqrtf(1.f + 1e-5f);
#pragma unroll
  for (int i = 0; i < 4; i++) {
#pragma unroll
    for (int r = 0; r < 4; r++) {
      int row = m0 + wm * 64 + i * 16 + rq * 4 + r;
      if (row < M) {
        int c = (row >> lshift) & 31;  // m = (bb*32+c)*L + j
        float scale = bng[c] * rs;
        float bias = bnb[c];
#pragma unroll
        for (int j = 0; j < 2; j++) {
          int col = n0 + wn * 32 + j * 16 + cn;
          if (col < NN) {
            size_t o = (size_t)row * NN + col;
            Out[o] = (acc[i][j][r] + Cin[o]) * scale + bias;
          }
        }
      }
    }
  }
}

// ROUND 31 tiny (64x64, M<=4096): small-M layers launch too few blocks for
// the 128x64 tile (M=4096: 256 blocks = 1 block/CU at only 4 waves; M<=2048:
// GPU partially idle, wall = per-block time). 64x64 halves per-block work
// (32 MFMA/round vs 64, 16KB staging vs 24KB) and doubles block count. Same
// verified BK=64 recipe: named scalar prefetch (4x float4), separate
// As0/As1/Bs0/Bs1 (4KB each), launch_bounds(256,4) (~70-reg live set, no
// spill). 4 waves each own 16 rows x 64 cols (acc[4]). Per-output pass/k
// order identical -> bit-identical (absmax 0.015625).
__global__ __launch_bounds__(256, 4) void mfma_gcn_tiny(PassSet s,
    const float* __restrict__ Cin, float* __restrict__ Out, int M,
    const float* __restrict__ bng, const float* __restrict__ bnb, int lshift) {
  __shared__ f16 As0[64 * 32];
  __shared__ f16 As1[64 * 32];
  __shared__ f16 Bs0[64 * 32];
  __shared__ f16 Bs1[64 * 32];
  int tid = threadIdx.x;
  int wave = tid >> 6, lane = tid & 63;
  int m0 = blockIdx.x * 64;
  int n0 = blockIdx.y * 64;
  int lm = lane & 15, kq = lane >> 4;  // frag: row lm, k-quad kq (8 k)
  // staging: 64 rows x 4 chunks of 8 f16 (one 4KB store op per buffer)
  int srow = tid >> 2, sc = tid & 3;
  int ar0 = m0 + srow;      if (ar0 > M - 1) ar0 = M - 1;
  size_t ag0 = (size_t)ar0 * KP + sc * 8;
  size_t bg0 = (size_t)(n0 + srow) * KP + sc * 8;  // rows n0..n0+63 (<512 pad)
  int sl0 = srow * 32 + ((sc ^ ((srow >> 1) & 3)) << 3);
  // fragment reads: row = wave*16 + lm -> key (lm>>1)&3
  int ach = kq ^ ((lm >> 1) & 3);

  floatx4 acc[4];
#pragma unroll
  for (int j = 0; j < 4; j++) acc[j] = (floatx4){0.f, 0.f, 0.f, 0.f};

  float4 pa0x, pa0y, pb0x, pb0y;
  {
    const f16* Ap = s.A[0];
    const f16* Bp = s.B[0];
    pa0x = *(const float4*)(Ap + ag0);
    pa0y = *(const float4*)(Ap + ag0 + 32);
    pb0x = *(const float4*)(Bp + bg0);
    pb0y = *(const float4*)(Bp + bg0 + 32);
  }
#pragma unroll
  for (int p = 0; p < 10; p++) {
    const f16* __restrict__ Ap = s.A[p];
    const f16* __restrict__ Bp = s.B[p];
    const f16* __restrict__ Apn = s.A[p < 9 ? p + 1 : p];
    const f16* __restrict__ Bpn = s.B[p < 9 ? p + 1 : p];
    for (int k0 = 0; k0 < KP; k0 += 64) {
      __syncthreads();  // prior compute done reading LDS
      *(float4*)(As0 + sl0) = pa0x;
      *(float4*)(As1 + sl0) = pa0y;
      *(float4*)(Bs0 + sl0) = pb0x;
      *(float4*)(Bs1 + sl0) = pb0y;
      __syncthreads();  // staging visible
      {  // prefetch next round (2 sub-strips); latency overlaps compute
        bool lastk = (k0 == KP - 64);
        const f16* An = lastk ? Apn : Ap;
        const f16* Bn = lastk ? Bpn : Bp;
        int kn = lastk ? 0 : k0 + 64;
        pa0x = *(const float4*)(An + ag0 + kn);
        pa0y = *(const float4*)(An + ag0 + kn + 32);
        pb0x = *(const float4*)(Bn + bg0 + kn);
        pb0y = *(const float4*)(Bn + bg0 + kn + 32);
      }
      {  // sub-strip 0 (k0)
        half8 a = *(const half8*)(As0 + (wave * 16 + lm) * 32 + ach * 8);
#pragma unroll
        for (int j = 0; j < 4; j++) {
          half8 b = *(const half8*)(Bs0 + (j * 16 + lm) * 32 + ach * 8);
          acc[j] = __builtin_amdgcn_mfma_f32_16x16x32_f16(a, b, acc[j], 0, 0, 0);
        }
      }
      {  // sub-strip 1 (k0+32)
        half8 a = *(const half8*)(As1 + (wave * 16 + lm) * 32 + ach * 8);
#pragma unroll
        for (int j = 0; j < 4; j++) {
          half8 b = *(const half8*)(Bs1 + (j * 16 + lm) * 32 + ach * 8);
          acc[j] = __builtin_amdgcn_mfma_f32_16x16x32_f16(a, b, acc[j], 0, 0, 0);
        }
      }
    }
  }
  // epilogue: C/D layout col = lane&15, row = (lane>>4)*4 + reg
  int cn = lane & 15, rq = lane >> 4;
  float rs = rsqrtf(1.f + 1e-5f);
#pragma unroll
  for (int r = 0; r < 4; r++) {
    int row = m0 + wave * 16 + rq * 4 + r;
    if (row < M) {
      int c = (row >> lshift) & 31;  // m = (bb*32+c)*L + j
      float scale = bng[c] * rs;
      float bias = bnb[c];
#pragma unroll
      for (int j = 0; j < 4; j++) {
        int col = n0 + j * 16 + cn;
        if (col < NN) {
          size_t o = (size_t)row * NN + col;
          Out[o] = (acc[j][r] + Cin[o]) * scale + bias;
        }
      }
    }
  }
}

// ROUND 27 wide (128x128, M>=8192): BK=64 spill-proofed, VERIFIED 123.5-125us,
// no spill. (256,3) vs (256,2) measured equivalent (r30 null); keep (256,3).
__global__ __launch_bounds__(256, 3) void mfma_gcn_wide(PassSet s,
    const float* __restrict__ Cin, float* __restrict__ Out, int M,
    const float* __restrict__ bng, const float* __restrict__ bnb, int lshift) {
  __shared__ f16 As0[128 * 32];
  __shared__ f16 As1[128 * 32];
  __shared__ f16 Bs0[128 * 32];
  __shared__ f16 Bs1[128 * 32];
  int tid = threadIdx.x;
  int wave = tid >> 6, lane = tid & 63;
  int wm = wave >> 1, wn = wave & 1;
  int m0 = blockIdx.x * 128;
  int n0 = blockIdx.y * 128;
  int lm = lane & 15, kq = lane >> 4;  // frag: row lm, k-quad kq (8 k)
  int srow = tid >> 2, sc = tid & 3;
  int ar0 = m0 + srow;      if (ar0 > M - 1) ar0 = M - 1;
  int ar1 = m0 + srow + 64; if (ar1 > M - 1) ar1 = M - 1;
  size_t ag0 = (size_t)ar0 * KP + sc * 8;
  size_t ag1 = (size_t)ar1 * KP + sc * 8;
  size_t bg0 = (size_t)(n0 + srow) * KP + sc * 8;
  size_t bg1 = (size_t)(n0 + srow + 64) * KP + sc * 8;  // <= 511 < 512 pad
  int sl0 = srow * 32 + ((sc ^ ((srow >> 1) & 3)) << 3);
  int sl1 = sl0 + 64 * 32;
  int ach = kq ^ ((lm >> 1) & 3);

  floatx4 acc[4][4];
#pragma unroll
  for (int i = 0; i < 4; i++)
#pragma unroll
    for (int j = 0; j < 4; j++) acc[i][j] = (floatx4){0.f, 0.f, 0.f, 0.f};

  // named scalars: paXY / pbXY, X = row-block (0: srow, 1: srow+64),
  // Y = sub-strip (0: k0, 1: k0+32)
  float4 pa00, pa01, pa10, pa11, pb00, pb01, pb10, pb11;
  {
    const f16* Ap = s.A[0];
    const f16* Bp = s.B[0];
    pa00 = *(const float4*)(Ap + ag0);
    pa01 = *(const float4*)(Ap + ag0 + 32);
    pa10 = *(const float4*)(Ap + ag1);
    pa11 = *(const float4*)(Ap + ag1 + 32);
    pb00 = *(const float4*)(Bp + bg0);
    pb01 = *(const float4*)(Bp + bg0 + 32);
    pb10 = *(const float4*)(Bp + bg1);
    pb11 = *(const float4*)(Bp + bg1 + 32);
  }
#pragma unroll
  for (int p = 0; p < 10; p++) {
    const f16* __restrict__ Ap = s.A[p];
    const f16* __restrict__ Bp = s.B[p];
    const f16* __restrict__ Apn = s.A[p < 9 ? p + 1 : p];
    const f16* __restrict__ Bpn = s.B[p < 9 ? p + 1 : p];
    for (int k0 = 0; k0 < KP; k0 += 64) {
      __syncthreads();  // prior compute done reading LDS
      *(float4*)(As0 + sl0) = pa00;
      *(float4*)(As1 + sl0) = pa01;
      *(float4*)(As0 + sl1) = pa10;
      *(float4*)(As1 + sl1) = pa11;
      *(float4*)(Bs0 + sl0) = pb00;
      *(float4*)(Bs1 + sl0) = pb01;
      *(float4*)(Bs0 + sl1) = pb10;
      *(float4*)(Bs1 + sl1) = pb11;
      __syncthreads();  // staging visible
      {  // prefetch next round (2 sub-strips); latency overlaps compute
        bool lastk = (k0 == KP - 64);
        const f16* An = lastk ? Apn : Ap;
        const f16* Bn = lastk ? Bpn : Bp;
        int kn = lastk ? 0 : k0 + 64;
        pa00 = *(const float4*)(An + ag0 + kn);
        pa01 = *(const float4*)(An + ag0 + kn + 32);
        pa10 = *(const float4*)(An + ag1 + kn);
        pa11 = *(const float4*)(An + ag1 + kn + 32);
        pb00 = *(const float4*)(Bn + bg0 + kn);
        pb01 = *(const float4*)(Bn + bg0 + kn + 32);
        pb10 = *(const float4*)(Bn + bg1 + kn);
        pb11 = *(const float4*)(Bn + bg1 + kn + 32);
      }
      {  // sub-strip 0 (k0)
        half8 a[4];
#pragma unroll
        for (int i = 0; i < 4; i++)
          a[i] = *(const half8*)(As0 + (wm * 64 + i * 16 + lm) * 32 + ach * 8);
#pragma unroll
        for (int j = 0; j < 4; j++) {
          half8 b = *(const half8*)(Bs0 + (wn * 64 + j * 16 + lm) * 32 + ach * 8);
#pragma unroll
          for (int i = 0; i < 4; i++)
            acc[i][j] = __builtin_amdgcn_mfma_f32_16x16x32_f16(a[i], b, acc[i][j], 0, 0, 0);
        }
      }
      {  // sub-strip 1 (k0+32)
        half8 a[4];
#pragma unroll
        for (int i = 0; i < 4; i++)
          a[i] = *(const half8*)(As1 + (wm * 64 + i * 16 + lm) * 32 + ach * 8);
#pragma unroll
        for (int j = 0; j < 4; j++) {
          half8 b = *(const half8*)(Bs1 + (wn * 64 + j * 16 + lm) * 32 + ach * 8);
#pragma unroll
          for (int i = 0; i < 4; i++)
            acc[i][j] = __builtin_amdgcn_mfma_f32_16x16x32_f16(a[i], b, acc[i][j], 0, 0, 0);
        }
      }
    }
  }
  int cn = lane & 15, rq = lane >> 4;
  float rs = rsqrtf(1.f + 1e-5f);
#pragma unroll
  for (int i = 0; i < 4; i++) {
#pragma unroll
    for (int r = 0; r < 4; r++) {
      int row = m0 + wm * 64 + i * 16 + rq * 4 + r;
      if (row < M) {
        int c = (row >> lshift) & 31;  // m = (bb*32+c)*L + j
        float scale = bng[c] * rs;
        float bias = bnb[c];
#pragma unroll
        for (int j = 0; j < 4; j++) {
          int col = n0 + wn * 64 + j * 16 + cn;
          if (col < NN) {
            size_t o = (size_t)row * NN + col;
            Out[o] = (acc[i][j][r] + Cin[o]) * scale + bias;
          }
        }
      }
    }
  }
}

// ---------------------------------------------------------------------------
// skip -> relu -> end1 -> relu -> end2. One block per (b, 20 n-values).
#define NB 20
#define NBP 21
__global__ __launch_bounds__(256) void final_kernel(const float* __restrict__ tap,
    const float* __restrict__ skw, const float* __restrict__ skb,
    const float* __restrict__ e1w, const float* __restrict__ e1b,
    const float* __restrict__ e2w, const float* __restrict__ e2b,
    float* __restrict__ out) {
  __shared__ float tapS[256][NBP];
  __shared__ float skS[256][NBP];
  __shared__ float e1S[512][NBP];
  int tid = threadIdx.x;
  int b = blockIdx.y;
  int n0 = blockIdx.x * NB;
  {
    int i = tid >> 5, c = tid & 31;
    const float* tp = tap + (((size_t)i * 8 + b) * 32 + c) * NN + n0;
#pragma unroll
    for (int v = 0; v < NB; v++) tapS[tid][v] = tp[v];
  }
  __syncthreads();
  {
    float bsum = 0.f;
#pragma unroll
    for (int i2 = 0; i2 < 8; i2++) bsum += skb[i2 * 256 + tid];
    float acc[NB];
#pragma unroll
    for (int v = 0; v < NB; v++) acc[v] = bsum;
#pragma unroll
    for (int i2 = 0; i2 < 8; i2++) {
      const float* wr = skw + ((size_t)i2 * 256 + tid) * 32;
#pragma unroll
      for (int cp = 0; cp < 32; cp++) {
        float w = wr[cp];
#pragma unroll
        for (int v = 0; v < NB; v++) acc[v] = fmaf(w, tapS[i2 * 32 + cp][v], acc[v]);
      }
    }
#pragma unroll
    for (int v = 0; v < NB; v++) skS[tid][v] = fmaxf(acc[v], 0.f);
  }
  __syncthreads();
#pragma unroll
  for (int h = 0; h < 2; h++) {
    int k = tid + h * 256;
    float bv = e1b[k];
    float acc[NB];
#pragma unroll
    for (int v = 0; v < NB; v++) acc[v] = bv;
    const float* wr = e1w + (size_t)k * 256;
    for (int o = 0; o < 256; o++) {
      float w = wr[o];
#pragma unroll
      for (int v = 0; v < NB; v++) acc[v] = fmaf(w, skS[o][v], acc[v]);
    }
#pragma unroll
    for (int v = 0; v < NB; v++) e1S[k][v] = fmaxf(acc[v], 0.f);
  }
  __syncthreads();
  if (tid < 12 * NB) {
    int q = tid / NB, v = tid % NB;
    float acc = e2b[q];
    const float* wr = e2w + (size_t)q * 512;
#pragma unroll 8
    for (int k = 0; k < 512; k++) acc = fmaf(wr[k], e1S[k][v], acc);
    out[((size_t)b * 12 + q) * NN + n0 + v] = acc;
  }
}

// ---------------------------------------------------------------------------
extern "C" void kernel_launch(void* const* d_in, const int* in_sizes, int n_in,
                              void* d_out, int out_size, void* d_ws, size_t ws_size,
                              hipStream_t stream) {
  const float* x       = (const float*)d_in[0];
  const float* A0      = (const float*)d_in[1];
  const float* start_w = (const float*)d_in[2];
  const float* start_b = (const float*)d_in[3];
  const float* filt_w  = (const float*)d_in[4];
  const float* filt_b  = (const float*)d_in[5];
  const float* gate_w  = (const float*)d_in[6];
  const float* gate_b  = (const float*)d_in[7];
  const float* skip_w  = (const float*)d_in[8];
  const float* skip_b  = (const float*)d_in[9];
  const float* gcn_w   = (const float*)d_in[10];
  const float* gcn_b   = (const float*)d_in[11];
  const float* bn_g    = (const float*)d_in[12];
  const float* bn_b    = (const float*)d_in[13];
  const float* nv1     = (const float*)d_in[14];
  const float* nv2     = (const float*)d_in[15];
  const float* e1w     = (const float*)d_in[16];
  const float* e1b     = (const float*)d_in[17];
  const float* e2w     = (const float*)d_in[18];
  const float* e2b     = (const float*)d_in[19];
  float* out = (float*)d_out;

  char* ws = (char*)d_ws;
  size_t off = 0;
  auto alloc = [&](size_t bytes) -> void* {
    void* p = (void*)(ws + off);
    off += (bytes + 255) & ~(size_t)255;
    return p;
  };
  float* adp   = (float*)alloc((size_t)NN * NN * 4);
  float* tap   = (float*)alloc((size_t)8 * 8 * 32 * NN * 4);
  float* xT    = (float*)alloc((size_t)16 * 256 * NN * 4);  // [b*2+ch][t][n]
  float* fwT   = (float*)alloc((size_t)16384 * 4);  // dconv weights [i][cp][tap][c]
  float* gwT   = (float*)alloc((size_t)16384 * 4);
  f16*   A0tH  = (f16*)alloc((size_t)KP * KP * 2);
  f16*   A0tL  = (f16*)alloc((size_t)KP * KP * 2);
  f16*   adptH = (f16*)alloc((size_t)KP * KP * 2);
  f16*   adptL = (f16*)alloc((size_t)KP * KP * 2);
  f16*   Q0H   = (f16*)alloc((size_t)KP * KP * 2);   // (A0^2)^T pair
  f16*   Q0L   = (f16*)alloc((size_t)KP * KP * 2);
  f16*   QdH   = (f16*)alloc((size_t)KP * KP * 2);   // (adp^2)^T pair
  f16*   QdL   = (f16*)alloc((size_t)KP * KP * 2);
  size_t fixed = off;

  // Workspace ladder: pick batch-group g and rows-per-batch slab capacity rpb.
  // Layer i (rows/batch = 32*L_i) runs in nCh = ceil(32*L_i/rpb) bb-chunks
  // (pointer offsets only, bit-identical math).
  int g = 1, rpb = 512;
  {
    const int gcand[4] = {8, 4, 2, 1};
    const int rcand[4] = {4096, 2048, 1024, 512};
    bool found = false;
    for (int gi = 0; gi < 4 && !found; gi++) {
      for (int ri = 0; ri < 4 && !found; ri++) {
        int gg = gcand[gi], rr = rcand[ri];
        if (4096 / rr > gg) continue;  // layer-0 chunk count must be <= g
        size_t need = fixed + (size_t)gg * 12288000ull +
                      6ull * gg * rr * KP * 2 + (1u << 20);
        if (need <= ws_size) { g = gg; rpb = rr; found = true; }
      }
    }
  }
  float* h128 = (float*)alloc((size_t)g * 8192000ull);
  float* h64  = (float*)alloc((size_t)g * 4096000ull);
  int R = g * rpb;  // slab rows per f16 array
  f16* slab   = (f16*)alloc(6ull * R * KP * 2);
  f16* P1a  = slab + 0ull * R * KP;
  f16* P2aH = slab + 1ull * R * KP;
  f16* P2aL = slab + 2ull * R * KP;
  f16* P1b  = slab + 3ull * R * KP;
  f16* P2bH = slab + 4ull * R * KP;
  f16* P2bL = slab + 5ull * R * KP;

  adp_kernel<<<NN, 256, 0, stream>>>(nv1, nv2, adp);
  xt_kernel<<<dim3(16, 8, 16), 256, 0, stream>>>(x, xT);
  wtr_kernel<<<64, 256, 0, stream>>>(filt_w, gate_w, fwT, gwT);
  bt_kernel<<<1024, 256, 0, stream>>>(A0, A0tH, A0tL);
  bt_kernel<<<1024, 256, 0, stream>>>(adp, adptH, adptL);
  sq_kernel<<<dim3(512, 2), 512, 0, stream>>>(A0, adp, Q0H, Q0L, QdH, QdL);
  padzero_kernel<<<(36 * R + 255) / 256, 256, 0, stream>>>((uint32_t*)slab, R);

  // out = H + P1a*A0 + P2a*A0^2 + P1b*adp + P2b*adp^2; P2 terms as hi/lo
  // pairs (3 passes, lo*lo dropped), P1 terms single-f16 (2 passes).
  PassSet ps{};
  {
    const f16* Alist[10] = {P1a, P1a, P2aH, P2aH, P2aL, P1b, P1b, P2bH, P2bH, P2bL};
    const f16* Blist[10] = {A0tH, A0tL, Q0H, Q0L, Q0H, adptH, adptL, QdH, QdL, QdH};
    for (int q = 0; q < 10; q++) { ps.A[q] = Alist[q]; ps.B[q] = Blist[q]; }
  }

  for (int b0 = 0; b0 < 8; b0 += g) {
    float* hprev = nullptr;
    int Lp = 256;
    for (int i = 0; i < 8; i++) {
      int L = Lp >> 1;  // 128,64,...,1
      if (i < 7) {
        float* hout = (i & 1) ? h64 : h128;
        int rows = 32 * L;                       // per batch element
        int nCh = (rows + rpb - 1) / rpb;        // bb-chunks (<= g, power of 2)
        if (nCh < 1) nCh = 1;
        int bbw = g / nCh;
        for (int ch = 0; ch < nCh; ch++) {
          int bb0 = ch * bbw;
          const float* hprev_c = hprev ? hprev + (size_t)bb0 * 32 * Lp * NN : nullptr;
          float* hout_c = hout + (size_t)bb0 * 32 * L * NN;
          if (i == 0) {
            dcm_kernel<true><<<dim3(L, bbw, 2), 256, 0, stream>>>(
                nullptr, xT, start_w, start_b,
                fwT + i * 2048, filt_b + i * 32, gwT + i * 2048, gate_b + i * 32,
                gcn_w + i * 5120, gcn_b + i * 32, hout_c,
                P1a, P2aH, P2aL, P1b, P2bH, P2bL,
                tap + (size_t)i * 8 * 32 * NN, Lp, L, b0 + bb0);
          } else {
            dcm_kernel<false><<<dim3(L, bbw, 2), 256, 0, stream>>>(
                hprev_c, nullptr, nullptr, nullptr,
                fwT + i * 2048, filt_b + i * 32, gwT + i * 2048, gate_b + i * 32,
                gcn_w + i * 5120, gcn_b + i * 32, hout_c,
                P1a, P2aH, P2aL, P1b, P2bH, P2bL,
                tap + (size_t)i * 8 * 32 * NN, Lp, L, b0 + bb0);
          }
          int M = bbw * 32 * L;
          if (M >= 8192) {
            int Mb = (M + 127) / 128;
            mfma_gcn_wide<<<dim3(Mb, 4), 256, 0, stream>>>(ps, hout_c, hout_c, M,
                                                           bn_g + i * 32, bn_b + i * 32, 7 - i);
          } else if (M > 4096) {
            int Mb = (M + 127) / 128;
            mfma_gcn<<<dim3(Mb, 8), 256, 0, stream>>>(ps, hout_c, hout_c, M,
                                                      bn_g + i * 32, bn_b + i * 32, 7 - i);
          } else {
            int Mb = (M + 63) / 64;
            mfma_gcn_tiny<<<dim3(Mb, 8), 256, 0, stream>>>(ps, hout_c, hout_c, M,
                                                           bn_g + i * 32, bn_b + i * 32, 7 - i);
          }
        }
        hprev = hout;
        Lp = L;
      } else {
        // layer 8: only the skip tap survives
        dcm_kernel<false><<<dim3(1, g, 2), 256, 0, stream>>>(
            hprev, nullptr, nullptr, nullptr,
            fwT + i * 2048, filt_b + i * 32, gwT + i * 2048, gate_b + i * 32,
            gcn_w, gcn_b, nullptr,
            P1a, P2aH, P2aL, P1b, P2bH, P2bL,
            tap + (size_t)i * 8 * 32 * NN, Lp, 1, b0);
      }
    }
  }
  final_kernel<<<dim3(25, 8), 256, 0, stream>>>(tap, skip_w, skip_b, e1w, e1b, e2w, e2b, out);
}

// Round 19
// 1734.604 us; speedup vs baseline: 1.0088x; 1.0088x over previous
//
#include <hip/hip_runtime.h>
#include <cstdint>
#include <cstddef>

#define NN 500
#define KP 512   // node dim padded to 512 for f16 MFMA operands

typedef _Float16 f16;
typedef _Float16 half8 __attribute__((ext_vector_type(8)));
typedef float floatx4 __attribute__((ext_vector_type(4)));

// 10 flattened GEMM passes: acc += A[p] * B[p]^T.
struct PassSet {
  const f16* A[10];
  const f16* B[10];
};

// ---------------------------------------------------------------------------
// adp = softmax(relu(E1 @ E2), axis=1)
__global__ __launch_bounds__(256) void adp_kernel(const float* __restrict__ e1,
                                                  const float* __restrict__ e2,
                                                  float* __restrict__ adp) {
  int r = blockIdx.x;
  int tid = threadIdx.x;
  __shared__ float red[256];
  __shared__ float e1row[16];
  if (tid < 10) e1row[tid] = e1[r * 10 + tid];
  __syncthreads();
  float z0, z1 = 0.f;
  {
    float acc = 0.f;
#pragma unroll
    for (int k = 0; k < 10; k++) acc += e1row[k] * e2[k * NN + tid];
    z0 = fmaxf(acc, 0.f);
  }
  bool has1 = (tid + 256) < NN;
  if (has1) {
    float acc = 0.f;
#pragma unroll
    for (int k = 0; k < 10; k++) acc += e1row[k] * e2[k * NN + tid + 256];
    z1 = fmaxf(acc, 0.f);
  }
  float mx = has1 ? fmaxf(z0, z1) : z0;
  red[tid] = mx;
  __syncthreads();
  for (int s = 128; s > 0; s >>= 1) {
    if (tid < s) red[tid] = fmaxf(red[tid], red[tid + s]);
    __syncthreads();
  }
  mx = red[0];
  __syncthreads();
  float ex0 = __expf(z0 - mx);
  float ex1 = has1 ? __expf(z1 - mx) : 0.f;
  red[tid] = ex0 + ex1;
  __syncthreads();
  for (int s = 128; s > 0; s >>= 1) {
    if (tid < s) red[tid] += red[tid + s];
    __syncthreads();
  }
  float inv = 1.f / red[0];
  adp[r * NN + tid] = ex0 * inv;
  if (has1) adp[r * NN + tid + 256] = ex1 * inv;
}

// ---------------------------------------------------------------------------
// xT[bc][t][n] = x[bc][n][t]  (coalesced reads for the fused layer-0 dconv)
__global__ __launch_bounds__(256) void xt_kernel(const float* __restrict__ x,
                                                 float* __restrict__ xT) {
  __shared__ float tile[32][33];
  int tx = threadIdx.x & 31, ty = threadIdx.x >> 5;
  int n0 = blockIdx.x * 32, t0 = blockIdx.y * 32, bc = blockIdx.z;
#pragma unroll
  for (int rr = 0; rr < 4; rr++) {
    int n = n0 + ty + rr * 8, t = t0 + tx;
    tile[ty + rr * 8][tx] = (n < NN) ? x[((size_t)bc * NN + n) * 256 + t] : 0.f;
  }
  __syncthreads();
#pragma unroll
  for (int rr = 0; rr < 4; rr++) {
    int t = t0 + ty + rr * 8, n = n0 + tx;
    if (n < NN) xT[((size_t)bc * 256 + t) * NN + n] = tile[tx][ty + rr * 8];
  }
}

// ---------------------------------------------------------------------------
// Transpose dconv weights [i][c][cp][tap] -> [i][cp][tap][c] (contiguous runs).
__global__ __launch_bounds__(256) void wtr_kernel(const float* __restrict__ fw,
                                                  const float* __restrict__ gw,
                                                  float* __restrict__ fwT,
                                                  float* __restrict__ gwT) {
  int idx = blockIdx.x * 256 + threadIdx.x;  // 8*32*32*2 = 16384
  if (idx >= 16384) return;
  int c = idx & 31;
  int rest = idx >> 5;   // (i*32+cp)*2+tap
  int tap = rest & 1;
  int cpi = rest >> 1;   // i*32+cp
  int cp = cpi & 31, i = cpi >> 5;
  size_t src = (((size_t)(i * 32 + c) * 32 + cp) * 2) + tap;
  fwT[idx] = fw[src];
  gwT[idx] = gw[src];
}

// ---------------------------------------------------------------------------
// B^T as f16 hi/lo pair: hi[w][v]+lo[w][v] ~= src[v][w], 512x512 zero-padded.
__global__ __launch_bounds__(256) void bt_kernel(const float* __restrict__ src,
                                                 f16* __restrict__ hi,
                                                 f16* __restrict__ lo) {
  int idx = blockIdx.x * 256 + threadIdx.x;  // 512*512 total
  int w = idx >> 9, v = idx & 511;
  float x = (w < NN && v < NN) ? src[v * NN + w] : 0.f;
  f16 h = (f16)x;
  hi[idx] = h;
  lo[idx] = (f16)(x - (float)h);
}

// ---------------------------------------------------------------------------
// Squared-matrix B^T pair: dst[w][v] = (src @ src)[v][w].
__global__ __launch_bounds__(512) void sq_kernel(const float* __restrict__ srcA,
                                                 const float* __restrict__ srcB,
                                                 f16* __restrict__ hiA, f16* __restrict__ loA,
                                                 f16* __restrict__ hiB, f16* __restrict__ loB) {
  const float* src = blockIdx.y == 0 ? srcA : srcB;
  f16* hi = blockIdx.y == 0 ? hiA : hiB;
  f16* lo = blockIdx.y == 0 ? loA : loB;
  int v = blockIdx.x;   // 0..511
  int w = threadIdx.x;  // 0..511
  __shared__ float vrow[512];
  vrow[w] = (v < NN && w < NN) ? src[v * NN + w] : 0.f;
  __syncthreads();
  float acc = 0.f;
  if (v < NN && w < NN) {
#pragma unroll 4
    for (int u = 0; u < NN; u++) acc = fmaf(vrow[u], src[u * NN + w], acc);
  }
  size_t o = (size_t)w * 512 + v;
  f16 h = (f16)acc;
  hi[o] = h;
  lo[o] = (f16)(acc - (float)h);
}

// ---------------------------------------------------------------------------
// Zero pad columns [500,512) of the six f16 P arrays (ws re-poisoned 0xAA).
__global__ __launch_bounds__(256) void padzero_kernel(uint32_t* __restrict__ slab, int R) {
  int idx = blockIdx.x * 256 + threadIdx.x;
  int total = 6 * R * 6;
  if (idx >= total) return;
  int a = idx / (R * 6);
  int rem = idx - a * R * 6;
  int row = rem / 6;
  int q = rem - row * 6;
  slab[(size_t)a * R * 256 + (size_t)row * 256 + 250 + q] = 0u;
}

// ---------------------------------------------------------------------------
// Fused (start-conv) + dilated-conv + gating + GCN channel-mix.
// ROUND 29 (kept): launch_bounds (256,2) freed the acc arrays from AGPR
// round-trips (total -114us). h residual stream fp32 (f16 failed r8).
// fw/gw TRANSPOSED [cp][tap][c]. All register-array index loops fully
// unrolled (r1). Grid: (j, bb, nhalf).
template <bool FUSED>
__global__ __launch_bounds__(256, 2) void dcm_kernel(
    const float* __restrict__ hprev, const float* __restrict__ xT,
    const float* __restrict__ sw, const float* __restrict__ sb,
    const float* __restrict__ fw, const float* __restrict__ fb,
    const float* __restrict__ gw, const float* __restrict__ gb,
    const float* __restrict__ cw, const float* __restrict__ cb,
    float* __restrict__ Hout,
    f16* __restrict__ P1a,
    f16* __restrict__ P2aH, f16* __restrict__ P2aL,
    f16* __restrict__ P1b,
    f16* __restrict__ P2bH, f16* __restrict__ P2bL,
    float* __restrict__ tapL,
    int Lp, int L, int b0) {
  int j = blockIdx.x, bb = blockIdx.y;
  int n0 = blockIdx.z * 256 + threadIdx.x;
  bool ok = (n0 < NN);
  int nc = ok ? n0 : (NN - 1);  // clamped index for always-valid loads
  size_t base = ((size_t)(bb * 32) * Lp + 2 * j) * NN;
  size_t cs = (size_t)Lp * NN;
  float x00 = 0.f, x01 = 0.f, x10 = 0.f, x11 = 0.f;
  if (FUSED) {
    const float* xb = xT + (size_t)(b0 + bb) * 2 * 256 * NN;
    x00 = xb[(size_t)(2 * j) * NN + nc];
    x01 = xb[(size_t)(2 * j + 1) * NN + nc];
    x10 = xb[(size_t)(256 + 2 * j) * NN + nc];
    x11 = xb[(size_t)(256 + 2 * j + 1) * NN + nc];
  }
  float accf[32], accg[32];
#pragma unroll
  for (int c = 0; c < 32; c++) {
    accf[c] = fb[c];
    accg[c] = gb[c];
  }
#pragma unroll 2
  for (int cp = 0; cp < 32; cp++) {
    float v0, v1;
    if (FUSED) {
      float w0 = sw[cp * 2], w1 = sw[cp * 2 + 1], bc = sb[cp];
      v0 = fmaf(w0, x00, fmaf(w1, x10, bc));
      v1 = fmaf(w0, x01, fmaf(w1, x11, bc));
    } else {
      const float* hp = hprev + base + cp * cs;
      v0 = hp[nc];
      v1 = hp[NN + nc];
    }
    const float* fwp = fw + cp * 64;  // [cp][tap][c]: 64 contiguous floats
    const float* gwp = gw + cp * 64;
#pragma unroll
    for (int c = 0; c < 32; c++) {
      float fw0 = fwp[c], fw1 = fwp[32 + c];
      float gw0 = gwp[c], gw1 = gwp[32 + c];
      accf[c] = fmaf(fw0, v0, accf[c]);
      accf[c] = fmaf(fw1, v1, accf[c]);
      accg[c] = fmaf(gw0, v0, accg[c]);
      accg[c] = fmaf(gw1, v1, accg[c]);
    }
  }
  float FG[32];
#pragma unroll
  for (int c = 0; c < 32; c++) {
    float E0 = __expf(2.f * accf[c]);
    float th0 = 1.f - 2.f / (E0 + 1.f);
    float sg0 = 1.f / (1.f + __expf(-accg[c]));
    FG[c] = th0 * sg0;
  }
  if (j == L - 1 && ok) {
    size_t tbase = ((size_t)(b0 + bb) * 32) * NN;
#pragma unroll
    for (int c = 0; c < 32; c++) {
      tapL[tbase + (size_t)c * NN + n0] = FG[c];
    }
  }
  if (Hout == nullptr) return;  // layer 8: only the skip tap survives
#pragma unroll 2
  for (int c = 0; c < 32; c++) {
    const float* wr = cw + c * 160;
    float cbc = cb[c];
    float h0 = cbc, p10 = 0.f, p20 = 0.f, q10 = 0.f, q20 = 0.f;
#pragma unroll
    for (int cp = 0; cp < 32; cp++) {
      float w0 = wr[cp], w1 = wr[32 + cp], w2 = wr[64 + cp];
      float w3 = wr[96 + cp], w4 = wr[128 + cp];
      float f0 = FG[cp];
      h0  = fmaf(w0, f0, h0);
      p10 = fmaf(w1, f0, p10);
      p20 = fmaf(w2, f0, p20);
      q10 = fmaf(w3, f0, q10);
      q20 = fmaf(w4, f0, q20);
    }
    // residual = hprev[2j+1] (start-conv output for layer 0)
    if (FUSED) {
      float sw0 = sw[c * 2], sw1 = sw[c * 2 + 1], sbc = sb[c];
      h0 += fmaf(sw0, x01, fmaf(sw1, x11, sbc));
    } else {
      const float* hr = hprev + ((size_t)(bb * 32 + c) * Lp + 2 * j + 1) * NN;
      h0 += hr[nc];
    }
    if (ok) {
      size_t mi = (size_t)(bb * 32 + c) * L + j;
      size_t o = mi * KP;
      f16 t;
      Hout[mi * NN + n0] = h0;
      P1a[o + n0] = (f16)p10;
      t = (f16)p20; P2aH[o + n0] = t; P2aL[o + n0] = (f16)(p20 - (float)t);
      P1b[o + n0] = (f16)q10;
      t = (f16)q20; P2bH[o + n0] = t; P2bL[o + n0] = (f16)(q20 - (float)t);
    }
  }
}

// ---------------------------------------------------------------------------
// ROUND 28 mfma_gcn (128x64, M<8192): BK=64, named scalar prefetch,
// separate As0/As1/Bs0/Bs1 LDS (24KB), launch_bounds(256,3). VERIFIED r28
// (no spill). r31's 64x64 tiny tile for M<=4096 REGRESSED (+37us: per-block
// wall dominated by fixed barrier-round latency which doesn't shrink with
// tile; KB/MFMA doubled) -> routing reverted to this kernel for all M<8192.
__global__ __launch_bounds__(256, 3) void mfma_gcn(PassSet s,
    const float* __restrict__ Cin, float* __restrict__ Out, int M,
    const float* __restrict__ bng, const float* __restrict__ bnb, int lshift) {
  __shared__ f16 As0[128 * 32];
  __shared__ f16 As1[128 * 32];
  __shared__ f16 Bs0[64 * 32];
  __shared__ f16 Bs1[64 * 32];
  int tid = threadIdx.x;
  int wave = tid >> 6, lane = tid & 63;
  int wm = wave >> 1, wn = wave & 1;
  int m0 = blockIdx.x * 128;
  int n0 = blockIdx.y * 64;
  int lm = lane & 15, kq = lane >> 4;  // frag: row lm, k-quad kq (8 k)
  // staging: A rows (tid>>2) and (tid>>2)+64 (16B chunk tid&3); B row (tid>>2)
  int srow = tid >> 2, sc = tid & 3;
  int ar0 = m0 + srow;      if (ar0 > M - 1) ar0 = M - 1;
  int ar1 = m0 + srow + 64; if (ar1 > M - 1) ar1 = M - 1;
  size_t ag0 = (size_t)ar0 * KP + sc * 8;
  size_t ag1 = (size_t)ar1 * KP + sc * 8;
  size_t bg0 = (size_t)(n0 + srow) * KP + sc * 8;  // rows n0..n0+63 (<512 pad)
  // XOR-swizzled LDS offsets (f16 units): off = row*32 + (chunk^((row>>1)&3))*8
  int sl0 = srow * 32 + ((sc ^ ((srow >> 1) & 3)) << 3);
  int sl1 = sl0 + 64 * 32;  // A second half
  // fragment reads: row = base16 + lm (base16 multiple of 16) -> key (lm>>1)&3
  int ach = kq ^ ((lm >> 1) & 3);

  floatx4 acc[4][2];
#pragma unroll
  for (int i = 0; i < 4; i++)
#pragma unroll
    for (int j = 0; j < 2; j++) acc[i][j] = (floatx4){0.f, 0.f, 0.f, 0.f};

  // named scalars: X = row-block (0: srow, 1: srow+64), suffix x/y = sub-strip
  float4 pa0x, pa0y, pa1x, pa1y, pb0x, pb0y;
  {
    const f16* Ap = s.A[0];
    const f16* Bp = s.B[0];
    pa0x = *(const float4*)(Ap + ag0);
    pa0y = *(const float4*)(Ap + ag0 + 32);
    pa1x = *(const float4*)(Ap + ag1);
    pa1y = *(const float4*)(Ap + ag1 + 32);
    pb0x = *(const float4*)(Bp + bg0);
    pb0y = *(const float4*)(Bp + bg0 + 32);
  }
#pragma unroll
  for (int p = 0; p < 10; p++) {
    const f16* __restrict__ Ap = s.A[p];
    const f16* __restrict__ Bp = s.B[p];
    const f16* __restrict__ Apn = s.A[p < 9 ? p + 1 : p];
    const f16* __restrict__ Bpn = s.B[p < 9 ? p + 1 : p];
    for (int k0 = 0; k0 < KP; k0 += 64) {
      __syncthreads();  // prior compute done reading LDS
      *(float4*)(As0 + sl0) = pa0x;
      *(float4*)(As1 + sl0) = pa0y;
      *(float4*)(As0 + sl1) = pa1x;
      *(float4*)(As1 + sl1) = pa1y;
      *(float4*)(Bs0 + sl0) = pb0x;
      *(float4*)(Bs1 + sl0) = pb0y;
      __syncthreads();  // staging visible
      {  // prefetch next round (2 sub-strips); latency overlaps compute
        bool lastk = (k0 == KP - 64);
        const f16* An = lastk ? Apn : Ap;
        const f16* Bn = lastk ? Bpn : Bp;
        int kn = lastk ? 0 : k0 + 64;
        pa0x = *(const float4*)(An + ag0 + kn);
        pa0y = *(const float4*)(An + ag0 + kn + 32);
        pa1x = *(const float4*)(An + ag1 + kn);
        pa1y = *(const float4*)(An + ag1 + kn + 32);
        pb0x = *(const float4*)(Bn + bg0 + kn);
        pb0y = *(const float4*)(Bn + bg0 + kn + 32);
      }
      {  // sub-strip 0 (k0)
        half8 a[4];
#pragma unroll
        for (int i = 0; i < 4; i++)
          a[i] = *(const half8*)(As0 + (wm * 64 + i * 16 + lm) * 32 + ach * 8);
#pragma unroll
        for (int j = 0; j < 2; j++) {
          half8 b = *(const half8*)(Bs0 + (wn * 32 + j * 16 + lm) * 32 + ach * 8);
#pragma unroll
          for (int i = 0; i < 4; i++)
            acc[i][j] = __builtin_amdgcn_mfma_f32_16x16x32_f16(a[i], b, acc[i][j], 0, 0, 0);
        }
      }
      {  // sub-strip 1 (k0+32)
        half8 a[4];
#pragma unroll
        for (int i = 0; i < 4; i++)
          a[i] = *(const half8*)(As1 + (wm * 64 + i * 16 + lm) * 32 + ach * 8);
#pragma unroll
        for (int j = 0; j < 2; j++) {
          half8 b = *(const half8*)(Bs1 + (wn * 32 + j * 16 + lm) * 32 + ach * 8);
#pragma unroll
          for (int i = 0; i < 4; i++)
            acc[i][j] = __builtin_amdgcn_mfma_f32_16x16x32_f16(a[i], b, acc[i][j], 0, 0, 0);
        }
      }
    }
  }
  // epilogue: C/D layout col = lane&15, row = (lane>>4)*4 + reg
  int cn = lane & 15, rq = lane >> 4;
  float rs = rsqrtf(1.f + 1e-5f);
#pragma unroll
  for (int i = 0; i < 4; i++) {
#pragma unroll
    for (int r = 0; r < 4; r++) {
      int row = m0 + wm * 64 + i * 16 + rq * 4 + r;
      if (row < M) {
        int c = (row >> lshift) & 31;  // m = (bb*32+c)*L + j
        float scale = bng[c] * rs;
        float bias = bnb[c];
#pragma unroll
        for (int j = 0; j < 2; j++) {
          int col = n0 + wn * 32 + j * 16 + cn;
          if (col < NN) {
            size_t o = (size_t)row * NN + col;
            Out[o] = (acc[i][j][r] + Cin[o]) * scale + bias;
          }
        }
      }
    }
  }
}

// ROUND 27 wide (128x128, M>=8192): BK=64 spill-proofed, VERIFIED 123.5-125us,
// no spill. (256,3) vs (256,2) measured equivalent (r30 null); keep (256,3).
__global__ __launch_bounds__(256, 3) void mfma_gcn_wide(PassSet s,
    const float* __restrict__ Cin, float* __restrict__ Out, int M,
    const float* __restrict__ bng, const float* __restrict__ bnb, int lshift) {
  __shared__ f16 As0[128 * 32];
  __shared__ f16 As1[128 * 32];
  __shared__ f16 Bs0[128 * 32];
  __shared__ f16 Bs1[128 * 32];
  int tid = threadIdx.x;
  int wave = tid >> 6, lane = tid & 63;
  int wm = wave >> 1, wn = wave & 1;
  int m0 = blockIdx.x * 128;
  int n0 = blockIdx.y * 128;
  int lm = lane & 15, kq = lane >> 4;  // frag: row lm, k-quad kq (8 k)
  int srow = tid >> 2, sc = tid & 3;
  int ar0 = m0 + srow;      if (ar0 > M - 1) ar0 = M - 1;
  int ar1 = m0 + srow + 64; if (ar1 > M - 1) ar1 = M - 1;
  size_t ag0 = (size_t)ar0 * KP + sc * 8;
  size_t ag1 = (size_t)ar1 * KP + sc * 8;
  size_t bg0 = (size_t)(n0 + srow) * KP + sc * 8;
  size_t bg1 = (size_t)(n0 + srow + 64) * KP + sc * 8;  // <= 511 < 512 pad
  int sl0 = srow * 32 + ((sc ^ ((srow >> 1) & 3)) << 3);
  int sl1 = sl0 + 64 * 32;
  int ach = kq ^ ((lm >> 1) & 3);

  floatx4 acc[4][4];
#pragma unroll
  for (int i = 0; i < 4; i++)
#pragma unroll
    for (int j = 0; j < 4; j++) acc[i][j] = (floatx4){0.f, 0.f, 0.f, 0.f};

  // named scalars: paXY / pbXY, X = row-block (0: srow, 1: srow+64),
  // Y = sub-strip (0: k0, 1: k0+32)
  float4 pa00, pa01, pa10, pa11, pb00, pb01, pb10, pb11;
  {
    const f16* Ap = s.A[0];
    const f16* Bp = s.B[0];
    pa00 = *(const float4*)(Ap + ag0);
    pa01 = *(const float4*)(Ap + ag0 + 32);
    pa10 = *(const float4*)(Ap + ag1);
    pa11 = *(const float4*)(Ap + ag1 + 32);
    pb00 = *(const float4*)(Bp + bg0);
    pb01 = *(const float4*)(Bp + bg0 + 32);
    pb10 = *(const float4*)(Bp + bg1);
    pb11 = *(const float4*)(Bp + bg1 + 32);
  }
#pragma unroll
  for (int p = 0; p < 10; p++) {
    const f16* __restrict__ Ap = s.A[p];
    const f16* __restrict__ Bp = s.B[p];
    const f16* __restrict__ Apn = s.A[p < 9 ? p + 1 : p];
    const f16* __restrict__ Bpn = s.B[p < 9 ? p + 1 : p];
    for (int k0 = 0; k0 < KP; k0 += 64) {
      __syncthreads();  // prior compute done reading LDS
      *(float4*)(As0 + sl0) = pa00;
      *(float4*)(As1 + sl0) = pa01;
      *(float4*)(As0 + sl1) = pa10;
      *(float4*)(As1 + sl1) = pa11;
      *(float4*)(Bs0 + sl0) = pb00;
      *(float4*)(Bs1 + sl0) = pb01;
      *(float4*)(Bs0 + sl1) = pb10;
      *(float4*)(Bs1 + sl1) = pb11;
      __syncthreads();  // staging visible
      {  // prefetch next round (2 sub-strips); latency overlaps compute
        bool lastk = (k0 == KP - 64);
        const f16* An = lastk ? Apn : Ap;
        const f16* Bn = lastk ? Bpn : Bp;
        int kn = lastk ? 0 : k0 + 64;
        pa00 = *(const float4*)(An + ag0 + kn);
        pa01 = *(const float4*)(An + ag0 + kn + 32);
        pa10 = *(const float4*)(An + ag1 + kn);
        pa11 = *(const float4*)(An + ag1 + kn + 32);
        pb00 = *(const float4*)(Bn + bg0 + kn);
        pb01 = *(const float4*)(Bn + bg0 + kn + 32);
        pb10 = *(const float4*)(Bn + bg1 + kn);
        pb11 = *(const float4*)(Bn + bg1 + kn + 32);
      }
      {  // sub-strip 0 (k0)
        half8 a[4];
#pragma unroll
        for (int i = 0; i < 4; i++)
          a[i] = *(const half8*)(As0 + (wm * 64 + i * 16 + lm) * 32 + ach * 8);
#pragma unroll
        for (int j = 0; j < 4; j++) {
          half8 b = *(const half8*)(Bs0 + (wn * 64 + j * 16 + lm) * 32 + ach * 8);
#pragma unroll
          for (int i = 0; i < 4; i++)
            acc[i][j] = __builtin_amdgcn_mfma_f32_16x16x32_f16(a[i], b, acc[i][j], 0, 0, 0);
        }
      }
      {  // sub-strip 1 (k0+32)
        half8 a[4];
#pragma unroll
        for (int i = 0; i < 4; i++)
          a[i] = *(const half8*)(As1 + (wm * 64 + i * 16 + lm) * 32 + ach * 8);
#pragma unroll
        for (int j = 0; j < 4; j++) {
          half8 b = *(const half8*)(Bs1 + (wn * 64 + j * 16 + lm) * 32 + ach * 8);
#pragma unroll
          for (int i = 0; i < 4; i++)
            acc[i][j] = __builtin_amdgcn_mfma_f32_16x16x32_f16(a[i], b, acc[i][j], 0, 0, 0);
        }
      }
    }
  }
  int cn = lane & 15, rq = lane >> 4;
  float rs = rsqrtf(1.f + 1e-5f);
#pragma unroll
  for (int i = 0; i < 4; i++) {
#pragma unroll
    for (int r = 0; r < 4; r++) {
      int row = m0 + wm * 64 + i * 16 + rq * 4 + r;
      if (row < M) {
        int c = (row >> lshift) & 31;  // m = (bb*32+c)*L + j
        float scale = bng[c] * rs;
        float bias = bnb[c];
#pragma unroll
        for (int j = 0; j < 4; j++) {
          int col = n0 + wn * 64 + j * 16 + cn;
          if (col < NN) {
            size_t o = (size_t)row * NN + col;
            Out[o] = (acc[i][j][r] + Cin[o]) * scale + bias;
          }
        }
      }
    }
  }
}

// ---------------------------------------------------------------------------
// skip -> relu -> end1 -> relu -> end2. One block per (b, 20 n-values).
#define NB 20
#define NBP 21
__global__ __launch_bounds__(256) void final_kernel(const float* __restrict__ tap,
    const float* __restrict__ skw, const float* __restrict__ skb,
    const float* __restrict__ e1w, const float* __restrict__ e1b,
    const float* __restrict__ e2w, const float* __restrict__ e2b,
    float* __restrict__ out) {
  __shared__ float tapS[256][NBP];
  __shared__ float skS[256][NBP];
  __shared__ float e1S[512][NBP];
  int tid = threadIdx.x;
  int b = blockIdx.y;
  int n0 = blockIdx.x * NB;
  {
    int i = tid >> 5, c = tid & 31;
    const float* tp = tap + (((size_t)i * 8 + b) * 32 + c) * NN + n0;
#pragma unroll
    for (int v = 0; v < NB; v++) tapS[tid][v] = tp[v];
  }
  __syncthreads();
  {
    float bsum = 0.f;
#pragma unroll
    for (int i2 = 0; i2 < 8; i2++) bsum += skb[i2 * 256 + tid];
    float acc[NB];
#pragma unroll
    for (int v = 0; v < NB; v++) acc[v] = bsum;
#pragma unroll
    for (int i2 = 0; i2 < 8; i2++) {
      const float* wr = skw + ((size_t)i2 * 256 + tid) * 32;
#pragma unroll
      for (int cp = 0; cp < 32; cp++) {
        float w = wr[cp];
#pragma unroll
        for (int v = 0; v < NB; v++) acc[v] = fmaf(w, tapS[i2 * 32 + cp][v], acc[v]);
      }
    }
#pragma unroll
    for (int v = 0; v < NB; v++) skS[tid][v] = fmaxf(acc[v], 0.f);
  }
  __syncthreads();
#pragma unroll
  for (int h = 0; h < 2; h++) {
    int k = tid + h * 256;
    float bv = e1b[k];
    float acc[NB];
#pragma unroll
    for (int v = 0; v < NB; v++) acc[v] = bv;
    const float* wr = e1w + (size_t)k * 256;
    for (int o = 0; o < 256; o++) {
      float w = wr[o];
#pragma unroll
      for (int v = 0; v < NB; v++) acc[v] = fmaf(w, skS[o][v], acc[v]);
    }
#pragma unroll
    for (int v = 0; v < NB; v++) e1S[k][v] = fmaxf(acc[v], 0.f);
  }
  __syncthreads();
  if (tid < 12 * NB) {
    int q = tid / NB, v = tid % NB;
    float acc = e2b[q];
    const float* wr = e2w + (size_t)q * 512;
#pragma unroll 8
    for (int k = 0; k < 512; k++) acc = fmaf(wr[k], e1S[k][v], acc);
    out[((size_t)b * 12 + q) * NN + n0 + v] = acc;
  }
}

// ---------------------------------------------------------------------------
extern "C" void kernel_launch(void* const* d_in, const int* in_sizes, int n_in,
                              void* d_out, int out_size, void* d_ws, size_t ws_size,
                              hipStream_t stream) {
  const float* x       = (const float*)d_in[0];
  const float* A0      = (const float*)d_in[1];
  const float* start_w = (const float*)d_in[2];
  const float* start_b = (const float*)d_in[3];
  const float* filt_w  = (const float*)d_in[4];
  const float* filt_b  = (const float*)d_in[5];
  const float* gate_w  = (const float*)d_in[6];
  const float* gate_b  = (const float*)d_in[7];
  const float* skip_w  = (const float*)d_in[8];
  const float* skip_b  = (const float*)d_in[9];
  const float* gcn_w   = (const float*)d_in[10];
  const float* gcn_b   = (const float*)d_in[11];
  const float* bn_g    = (const float*)d_in[12];
  const float* bn_b    = (const float*)d_in[13];
  const float* nv1     = (const float*)d_in[14];
  const float* nv2     = (const float*)d_in[15];
  const float* e1w     = (const float*)d_in[16];
  const float* e1b     = (const float*)d_in[17];
  const float* e2w     = (const float*)d_in[18];
  const float* e2b     = (const float*)d_in[19];
  float* out = (float*)d_out;

  char* ws = (char*)d_ws;
  size_t off = 0;
  auto alloc = [&](size_t bytes) -> void* {
    void* p = (void*)(ws + off);
    off += (bytes + 255) & ~(size_t)255;
    return p;
  };
  float* adp   = (float*)alloc((size_t)NN * NN * 4);
  float* tap   = (float*)alloc((size_t)8 * 8 * 32 * NN * 4);
  float* xT    = (float*)alloc((size_t)16 * 256 * NN * 4);  // [b*2+ch][t][n]
  float* fwT   = (float*)alloc((size_t)16384 * 4);  // dconv weights [i][cp][tap][c]
  float* gwT   = (float*)alloc((size_t)16384 * 4);
  f16*   A0tH  = (f16*)alloc((size_t)KP * KP * 2);
  f16*   A0tL  = (f16*)alloc((size_t)KP * KP * 2);
  f16*   adptH = (f16*)alloc((size_t)KP * KP * 2);
  f16*   adptL = (f16*)alloc((size_t)KP * KP * 2);
  f16*   Q0H   = (f16*)alloc((size_t)KP * KP * 2);   // (A0^2)^T pair
  f16*   Q0L   = (f16*)alloc((size_t)KP * KP * 2);
  f16*   QdH   = (f16*)alloc((size_t)KP * KP * 2);   // (adp^2)^T pair
  f16*   QdL   = (f16*)alloc((size_t)KP * KP * 2);
  size_t fixed = off;

  // Workspace ladder: pick batch-group g and rows-per-batch slab capacity rpb.
  // Layer i (rows/batch = 32*L_i) runs in nCh = ceil(32*L_i/rpb) bb-chunks
  // (pointer offsets only, bit-identical math).
  int g = 1, rpb = 512;
  {
    const int gcand[4] = {8, 4, 2, 1};
    const int rcand[4] = {4096, 2048, 1024, 512};
    bool found = false;
    for (int gi = 0; gi < 4 && !found; gi++) {
      for (int ri = 0; ri < 4 && !found; ri++) {
        int gg = gcand[gi], rr = rcand[ri];
        if (4096 / rr > gg) continue;  // layer-0 chunk count must be <= g
        size_t need = fixed + (size_t)gg * 12288000ull +
                      6ull * gg * rr * KP * 2 + (1u << 20);
        if (need <= ws_size) { g = gg; rpb = rr; found = true; }
      }
    }
  }
  float* h128 = (float*)alloc((size_t)g * 8192000ull);
  float* h64  = (float*)alloc((size_t)g * 4096000ull);
  int R = g * rpb;  // slab rows per f16 array
  f16* slab   = (f16*)alloc(6ull * R * KP * 2);
  f16* P1a  = slab + 0ull * R * KP;
  f16* P2aH = slab + 1ull * R * KP;
  f16* P2aL = slab + 2ull * R * KP;
  f16* P1b  = slab + 3ull * R * KP;
  f16* P2bH = slab + 4ull * R * KP;
  f16* P2bL = slab + 5ull * R * KP;

  adp_kernel<<<NN, 256, 0, stream>>>(nv1, nv2, adp);
  xt_kernel<<<dim3(16, 8, 16), 256, 0, stream>>>(x, xT);
  wtr_kernel<<<64, 256, 0, stream>>>(filt_w, gate_w, fwT, gwT);
  bt_kernel<<<1024, 256, 0, stream>>>(A0, A0tH, A0tL);
  bt_kernel<<<1024, 256, 0, stream>>>(adp, adptH, adptL);
  sq_kernel<<<dim3(512, 2), 512, 0, stream>>>(A0, adp, Q0H, Q0L, QdH, QdL);
  padzero_kernel<<<(36 * R + 255) / 256, 256, 0, stream>>>((uint32_t*)slab, R);

  // out = H + P1a*A0 + P2a*A0^2 + P1b*adp + P2b*adp^2; P2 terms as hi/lo
  // pairs (3 passes, lo*lo dropped), P1 terms single-f16 (2 passes).
  PassSet ps{};
  {
    const f16* Alist[10] = {P1a, P1a, P2aH, P2aH, P2aL, P1b, P1b, P2bH, P2bH, P2bL};
    const f16* Blist[10] = {A0tH, A0tL, Q0H, Q0L, Q0H, adptH, adptL, QdH, QdL, QdH};
    for (int q = 0; q < 10; q++) { ps.A[q] = Alist[q]; ps.B[q] = Blist[q]; }
  }

  for (int b0 = 0; b0 < 8; b0 += g) {
    float* hprev = nullptr;
    int Lp = 256;
    for (int i = 0; i < 8; i++) {
      int L = Lp >> 1;  // 128,64,...,1
      if (i < 7) {
        float* hout = (i & 1) ? h64 : h128;
        int rows = 32 * L;                       // per batch element
        int nCh = (rows + rpb - 1) / rpb;        // bb-chunks (<= g, power of 2)
        if (nCh < 1) nCh = 1;
        int bbw = g / nCh;
        for (int ch = 0; ch < nCh; ch++) {
          int bb0 = ch * bbw;
          const float* hprev_c = hprev ? hprev + (size_t)bb0 * 32 * Lp * NN : nullptr;
          float* hout_c = hout + (size_t)bb0 * 32 * L * NN;
          if (i == 0) {
            dcm_kernel<true><<<dim3(L, bbw, 2), 256, 0, stream>>>(
                nullptr, xT, start_w, start_b,
                fwT + i * 2048, filt_b + i * 32, gwT + i * 2048, gate_b + i * 32,
                gcn_w + i * 5120, gcn_b + i * 32, hout_c,
                P1a, P2aH, P2aL, P1b, P2bH, P2bL,
                tap + (size_t)i * 8 * 32 * NN, Lp, L, b0 + bb0);
          } else {
            dcm_kernel<false><<<dim3(L, bbw, 2), 256, 0, stream>>>(
                hprev_c, nullptr, nullptr, nullptr,
                fwT + i * 2048, filt_b + i * 32, gwT + i * 2048, gate_b + i * 32,
                gcn_w + i * 5120, gcn_b + i * 32, hout_c,
                P1a, P2aH, P2aL, P1b, P2bH, P2bL,
                tap + (size_t)i * 8 * 32 * NN, Lp, L, b0 + bb0);
          }
          int M = bbw * 32 * L;
          int Mb = (M + 127) / 128;
          if (M >= 8192) {
            mfma_gcn_wide<<<dim3(Mb, 4), 256, 0, stream>>>(ps, hout_c, hout_c, M,
                                                           bn_g + i * 32, bn_b + i * 32, 7 - i);
          } else {
            mfma_gcn<<<dim3(Mb, 8), 256, 0, stream>>>(ps, hout_c, hout_c, M,
                                                      bn_g + i * 32, bn_b + i * 32, 7 - i);
          }
        }
        hprev = hout;
        Lp = L;
      } else {
        // layer 8: only the skip tap survives
        dcm_kernel<false><<<dim3(1, g, 2), 256, 0, stream>>>(
            hprev, nullptr, nullptr, nullptr,
            fwT + i * 2048, filt_b + i * 32, gwT + i * 2048, gate_b + i * 32,
            gcn_w, gcn_b, nullptr,
            P1a, P2aH, P2aL, P1b, P2bH, P2bL,
            tap + (size_t)i * 8 * 32 * NN, Lp, 1, b0);
      }
    }
  }
  final_kernel<<<dim3(25, 8), 256, 0, stream>>>(tap, skip_w, skip_b, e1w, e1b, e2w, e2b, out);
}

// Round 20
// 1711.415 us; speedup vs baseline: 1.0225x; 1.0135x over previous
//
#include <hip/hip_runtime.h>
#include <cstdint>
#include <cstddef>

#define NN 500
#define KP 512   // node dim padded to 512 for f16 MFMA operands

typedef _Float16 f16;
typedef _Float16 half8 __attribute__((ext_vector_type(8)));
typedef float floatx4 __attribute__((ext_vector_type(4)));

// 10 flattened GEMM passes: acc += A[p] * B[p]^T.
struct PassSet {
  const f16* A[10];
  const f16* B[10];
};

// ---------------------------------------------------------------------------
// adp = softmax(relu(E1 @ E2), axis=1)
__global__ __launch_bounds__(256) void adp_kernel(const float* __restrict__ e1,
                                                  const float* __restrict__ e2,
                                                  float* __restrict__ adp) {
  int r = blockIdx.x;
  int tid = threadIdx.x;
  __shared__ float red[256];
  __shared__ float e1row[16];
  if (tid < 10) e1row[tid] = e1[r * 10 + tid];
  __syncthreads();
  float z0, z1 = 0.f;
  {
    float acc = 0.f;
#pragma unroll
    for (int k = 0; k < 10; k++) acc += e1row[k] * e2[k * NN + tid];
    z0 = fmaxf(acc, 0.f);
  }
  bool has1 = (tid + 256) < NN;
  if (has1) {
    float acc = 0.f;
#pragma unroll
    for (int k = 0; k < 10; k++) acc += e1row[k] * e2[k * NN + tid + 256];
    z1 = fmaxf(acc, 0.f);
  }
  float mx = has1 ? fmaxf(z0, z1) : z0;
  red[tid] = mx;
  __syncthreads();
  for (int s = 128; s > 0; s >>= 1) {
    if (tid < s) red[tid] = fmaxf(red[tid], red[tid + s]);
    __syncthreads();
  }
  mx = red[0];
  __syncthreads();
  float ex0 = __expf(z0 - mx);
  float ex1 = has1 ? __expf(z1 - mx) : 0.f;
  red[tid] = ex0 + ex1;
  __syncthreads();
  for (int s = 128; s > 0; s >>= 1) {
    if (tid < s) red[tid] += red[tid + s];
    __syncthreads();
  }
  float inv = 1.f / red[0];
  adp[r * NN + tid] = ex0 * inv;
  if (has1) adp[r * NN + tid + 256] = ex1 * inv;
}

// ---------------------------------------------------------------------------
// xT[bc][t][n] = x[bc][n][t]  (coalesced reads for the fused layer-0 dconv)
__global__ __launch_bounds__(256) void xt_kernel(const float* __restrict__ x,
                                                 float* __restrict__ xT) {
  __shared__ float tile[32][33];
  int tx = threadIdx.x & 31, ty = threadIdx.x >> 5;
  int n0 = blockIdx.x * 32, t0 = blockIdx.y * 32, bc = blockIdx.z;
#pragma unroll
  for (int rr = 0; rr < 4; rr++) {
    int n = n0 + ty + rr * 8, t = t0 + tx;
    tile[ty + rr * 8][tx] = (n < NN) ? x[((size_t)bc * NN + n) * 256 + t] : 0.f;
  }
  __syncthreads();
#pragma unroll
  for (int rr = 0; rr < 4; rr++) {
    int t = t0 + ty + rr * 8, n = n0 + tx;
    if (n < NN) xT[((size_t)bc * 256 + t) * NN + n] = tile[tx][ty + rr * 8];
  }
}

// ---------------------------------------------------------------------------
// Transpose dconv weights [i][c][cp][tap] -> [i][cp][tap][c] (contiguous runs).
__global__ __launch_bounds__(256) void wtr_kernel(const float* __restrict__ fw,
                                                  const float* __restrict__ gw,
                                                  float* __restrict__ fwT,
                                                  float* __restrict__ gwT) {
  int idx = blockIdx.x * 256 + threadIdx.x;  // 8*32*32*2 = 16384
  if (idx >= 16384) return;
  int c = idx & 31;
  int rest = idx >> 5;   // (i*32+cp)*2+tap
  int tap = rest & 1;
  int cpi = rest >> 1;   // i*32+cp
  int cp = cpi & 31, i = cpi >> 5;
  size_t src = (((size_t)(i * 32 + c) * 32 + cp) * 2) + tap;
  fwT[idx] = fw[src];
  gwT[idx] = gw[src];
}

// ---------------------------------------------------------------------------
// B^T as f16 hi/lo pair: hi[w][v]+lo[w][v] ~= src[v][w], 512x512 zero-padded.
__global__ __launch_bounds__(256) void bt_kernel(const float* __restrict__ src,
                                                 f16* __restrict__ hi,
                                                 f16* __restrict__ lo) {
  int idx = blockIdx.x * 256 + threadIdx.x;  // 512*512 total
  int w = idx >> 9, v = idx & 511;
  float x = (w < NN && v < NN) ? src[v * NN + w] : 0.f;
  f16 h = (f16)x;
  hi[idx] = h;
  lo[idx] = (f16)(x - (float)h);
}

// ---------------------------------------------------------------------------
// Squared-matrix B^T pair: dst[w][v] = (src @ src)[v][w].
__global__ __launch_bounds__(512) void sq_kernel(const float* __restrict__ srcA,
                                                 const float* __restrict__ srcB,
                                                 f16* __restrict__ hiA, f16* __restrict__ loA,
                                                 f16* __restrict__ hiB, f16* __restrict__ loB) {
  const float* src = blockIdx.y == 0 ? srcA : srcB;
  f16* hi = blockIdx.y == 0 ? hiA : hiB;
  f16* lo = blockIdx.y == 0 ? loA : loB;
  int v = blockIdx.x;   // 0..511
  int w = threadIdx.x;  // 0..511
  __shared__ float vrow[512];
  vrow[w] = (v < NN && w < NN) ? src[v * NN + w] : 0.f;
  __syncthreads();
  float acc = 0.f;
  if (v < NN && w < NN) {
#pragma unroll 4
    for (int u = 0; u < NN; u++) acc = fmaf(vrow[u], src[u * NN + w], acc);
  }
  size_t o = (size_t)w * 512 + v;
  f16 h = (f16)acc;
  hi[o] = h;
  lo[o] = (f16)(acc - (float)h);
}

// ---------------------------------------------------------------------------
// Zero pad columns [500,512) of the six f16 P arrays (ws re-poisoned 0xAA).
__global__ __launch_bounds__(256) void padzero_kernel(uint32_t* __restrict__ slab, int R) {
  int idx = blockIdx.x * 256 + threadIdx.x;
  int total = 6 * R * 6;
  if (idx >= total) return;
  int a = idx / (R * 6);
  int rem = idx - a * R * 6;
  int row = rem / 6;
  int q = rem - row * 6;
  slab[(size_t)a * R * 256 + (size_t)row * 256 + 250 + q] = 0u;
}

// ---------------------------------------------------------------------------
// Fused (start-conv) + dilated-conv + gating + GCN channel-mix.
// ROUND 33: dconv cp-loop unroll 2 -> 4. dcm non-FUSED runs at VALUBusy 51%
// (half stalls); the stall source is the hprev loads -- only 4 in flight per
// issue group at unroll 2 vs L3/HBM latency. (256,2)'s ~256-VGPR budget has
// ample headroom for 8 in flight. FMA order per accumulator unchanged by
// unrolling (cp still ascends) -> bit-identical (absmax 0.015625).
// ROUND 29 (kept): launch_bounds (256,2) freed acc arrays from AGPR
// round-trips. h residual fp32 (f16 failed r8). fw/gw TRANSPOSED
// [cp][tap][c]. Register-array loops fully unrolled (r1). Grid: (j,bb,nhalf).
template <bool FUSED>
__global__ __launch_bounds__(256, 2) void dcm_kernel(
    const float* __restrict__ hprev, const float* __restrict__ xT,
    const float* __restrict__ sw, const float* __restrict__ sb,
    const float* __restrict__ fw, const float* __restrict__ fb,
    const float* __restrict__ gw, const float* __restrict__ gb,
    const float* __restrict__ cw, const float* __restrict__ cb,
    float* __restrict__ Hout,
    f16* __restrict__ P1a,
    f16* __restrict__ P2aH, f16* __restrict__ P2aL,
    f16* __restrict__ P1b,
    f16* __restrict__ P2bH, f16* __restrict__ P2bL,
    float* __restrict__ tapL,
    int Lp, int L, int b0) {
  int j = blockIdx.x, bb = blockIdx.y;
  int n0 = blockIdx.z * 256 + threadIdx.x;
  bool ok = (n0 < NN);
  int nc = ok ? n0 : (NN - 1);  // clamped index for always-valid loads
  size_t base = ((size_t)(bb * 32) * Lp + 2 * j) * NN;
  size_t cs = (size_t)Lp * NN;
  float x00 = 0.f, x01 = 0.f, x10 = 0.f, x11 = 0.f;
  if (FUSED) {
    const float* xb = xT + (size_t)(b0 + bb) * 2 * 256 * NN;
    x00 = xb[(size_t)(2 * j) * NN + nc];
    x01 = xb[(size_t)(2 * j + 1) * NN + nc];
    x10 = xb[(size_t)(256 + 2 * j) * NN + nc];
    x11 = xb[(size_t)(256 + 2 * j + 1) * NN + nc];
  }
  float accf[32], accg[32];
#pragma unroll
  for (int c = 0; c < 32; c++) {
    accf[c] = fb[c];
    accg[c] = gb[c];
  }
#pragma unroll 4
  for (int cp = 0; cp < 32; cp++) {
    float v0, v1;
    if (FUSED) {
      float w0 = sw[cp * 2], w1 = sw[cp * 2 + 1], bc = sb[cp];
      v0 = fmaf(w0, x00, fmaf(w1, x10, bc));
      v1 = fmaf(w0, x01, fmaf(w1, x11, bc));
    } else {
      const float* hp = hprev + base + cp * cs;
      v0 = hp[nc];
      v1 = hp[NN + nc];
    }
    const float* fwp = fw + cp * 64;  // [cp][tap][c]: 64 contiguous floats
    const float* gwp = gw + cp * 64;
#pragma unroll
    for (int c = 0; c < 32; c++) {
      float fw0 = fwp[c], fw1 = fwp[32 + c];
      float gw0 = gwp[c], gw1 = gwp[32 + c];
      accf[c] = fmaf(fw0, v0, accf[c]);
      accf[c] = fmaf(fw1, v1, accf[c]);
      accg[c] = fmaf(gw0, v0, accg[c]);
      accg[c] = fmaf(gw1, v1, accg[c]);
    }
  }
  float FG[32];
#pragma unroll
  for (int c = 0; c < 32; c++) {
    float E0 = __expf(2.f * accf[c]);
    float th0 = 1.f - 2.f / (E0 + 1.f);
    float sg0 = 1.f / (1.f + __expf(-accg[c]));
    FG[c] = th0 * sg0;
  }
  if (j == L - 1 && ok) {
    size_t tbase = ((size_t)(b0 + bb) * 32) * NN;
#pragma unroll
    for (int c = 0; c < 32; c++) {
      tapL[tbase + (size_t)c * NN + n0] = FG[c];
    }
  }
  if (Hout == nullptr) return;  // layer 8: only the skip tap survives
#pragma unroll 2
  for (int c = 0; c < 32; c++) {
    const float* wr = cw + c * 160;
    float cbc = cb[c];
    float h0 = cbc, p10 = 0.f, p20 = 0.f, q10 = 0.f, q20 = 0.f;
#pragma unroll
    for (int cp = 0; cp < 32; cp++) {
      float w0 = wr[cp], w1 = wr[32 + cp], w2 = wr[64 + cp];
      float w3 = wr[96 + cp], w4 = wr[128 + cp];
      float f0 = FG[cp];
      h0  = fmaf(w0, f0, h0);
      p10 = fmaf(w1, f0, p10);
      p20 = fmaf(w2, f0, p20);
      q10 = fmaf(w3, f0, q10);
      q20 = fmaf(w4, f0, q20);
    }
    // residual = hprev[2j+1] (start-conv output for layer 0)
    if (FUSED) {
      float sw0 = sw[c * 2], sw1 = sw[c * 2 + 1], sbc = sb[c];
      h0 += fmaf(sw0, x01, fmaf(sw1, x11, sbc));
    } else {
      const float* hr = hprev + ((size_t)(bb * 32 + c) * Lp + 2 * j + 1) * NN;
      h0 += hr[nc];
    }
    if (ok) {
      size_t mi = (size_t)(bb * 32 + c) * L + j;
      size_t o = mi * KP;
      f16 t;
      Hout[mi * NN + n0] = h0;
      P1a[o + n0] = (f16)p10;
      t = (f16)p20; P2aH[o + n0] = t; P2aL[o + n0] = (f16)(p20 - (float)t);
      P1b[o + n0] = (f16)q10;
      t = (f16)q20; P2bH[o + n0] = t; P2bL[o + n0] = (f16)(q20 - (float)t);
    }
  }
}

// ---------------------------------------------------------------------------
// ROUND 28 mfma_gcn (128x64, M<8192): BK=64, named scalar prefetch,
// separate As0/As1/Bs0/Bs1 LDS (24KB), launch_bounds(256,3). VERIFIED r28
// (no spill). Unchanged.
__global__ __launch_bounds__(256, 3) void mfma_gcn(PassSet s,
    const float* __restrict__ Cin, float* __restrict__ Out, int M,
    const float* __restrict__ bng, const float* __restrict__ bnb, int lshift) {
  __shared__ f16 As0[128 * 32];
  __shared__ f16 As1[128 * 32];
  __shared__ f16 Bs0[64 * 32];
  __shared__ f16 Bs1[64 * 32];
  int tid = threadIdx.x;
  int wave = tid >> 6, lane = tid & 63;
  int wm = wave >> 1, wn = wave & 1;
  int m0 = blockIdx.x * 128;
  int n0 = blockIdx.y * 64;
  int lm = lane & 15, kq = lane >> 4;  // frag: row lm, k-quad kq (8 k)
  // staging: A rows (tid>>2) and (tid>>2)+64 (16B chunk tid&3); B row (tid>>2)
  int srow = tid >> 2, sc = tid & 3;
  int ar0 = m0 + srow;      if (ar0 > M - 1) ar0 = M - 1;
  int ar1 = m0 + srow + 64; if (ar1 > M - 1) ar1 = M - 1;
  size_t ag0 = (size_t)ar0 * KP + sc * 8;
  size_t ag1 = (size_t)ar1 * KP + sc * 8;
  size_t bg0 = (size_t)(n0 + srow) * KP + sc * 8;  // rows n0..n0+63 (<512 pad)
  // XOR-swizzled LDS offsets (f16 units): off = row*32 + (chunk^((row>>1)&3))*8
  int sl0 = srow * 32 + ((sc ^ ((srow >> 1) & 3)) << 3);
  int sl1 = sl0 + 64 * 32;  // A second half
  // fragment reads: row = base16 + lm (base16 multiple of 16) -> key (lm>>1)&3
  int ach = kq ^ ((lm >> 1) & 3);

  floatx4 acc[4][2];
#pragma unroll
  for (int i = 0; i < 4; i++)
#pragma unroll
    for (int j = 0; j < 2; j++) acc[i][j] = (floatx4){0.f, 0.f, 0.f, 0.f};

  // named scalars: X = row-block (0: srow, 1: srow+64), suffix x/y = sub-strip
  float4 pa0x, pa0y, pa1x, pa1y, pb0x, pb0y;
  {
    const f16* Ap = s.A[0];
    const f16* Bp = s.B[0];
    pa0x = *(const float4*)(Ap + ag0);
    pa0y = *(const float4*)(Ap + ag0 + 32);
    pa1x = *(const float4*)(Ap + ag1);
    pa1y = *(const float4*)(Ap + ag1 + 32);
    pb0x = *(const float4*)(Bp + bg0);
    pb0y = *(const float4*)(Bp + bg0 + 32);
  }
#pragma unroll
  for (int p = 0; p < 10; p++) {
    const f16* __restrict__ Ap = s.A[p];
    const f16* __restrict__ Bp = s.B[p];
    const f16* __restrict__ Apn = s.A[p < 9 ? p + 1 : p];
    const f16* __restrict__ Bpn = s.B[p < 9 ? p + 1 : p];
    for (int k0 = 0; k0 < KP; k0 += 64) {
      __syncthreads();  // prior compute done reading LDS
      *(float4*)(As0 + sl0) = pa0x;
      *(float4*)(As1 + sl0) = pa0y;
      *(float4*)(As0 + sl1) = pa1x;
      *(float4*)(As1 + sl1) = pa1y;
      *(float4*)(Bs0 + sl0) = pb0x;
      *(float4*)(Bs1 + sl0) = pb0y;
      __syncthreads();  // staging visible
      {  // prefetch next round (2 sub-strips); latency overlaps compute
        bool lastk = (k0 == KP - 64);
        const f16* An = lastk ? Apn : Ap;
        const f16* Bn = lastk ? Bpn : Bp;
        int kn = lastk ? 0 : k0 + 64;
        pa0x = *(const float4*)(An + ag0 + kn);
        pa0y = *(const float4*)(An + ag0 + kn + 32);
        pa1x = *(const float4*)(An + ag1 + kn);
        pa1y = *(const float4*)(An + ag1 + kn + 32);
        pb0x = *(const float4*)(Bn + bg0 + kn);
        pb0y = *(const float4*)(Bn + bg0 + kn + 32);
      }
      {  // sub-strip 0 (k0)
        half8 a[4];
#pragma unroll
        for (int i = 0; i < 4; i++)
          a[i] = *(const half8*)(As0 + (wm * 64 + i * 16 + lm) * 32 + ach * 8);
#pragma unroll
        for (int j = 0; j < 2; j++) {
          half8 b = *(const half8*)(Bs0 + (wn * 32 + j * 16 + lm) * 32 + ach * 8);
#pragma unroll
          for (int i = 0; i < 4; i++)
            acc[i][j] = __builtin_amdgcn_mfma_f32_16x16x32_f16(a[i], b, acc[i][j], 0, 0, 0);
        }
      }
      {  // sub-strip 1 (k0+32)
        half8 a[4];
#pragma unroll
        for (int i = 0; i < 4; i++)
          a[i] = *(const half8*)(As1 + (wm * 64 + i * 16 + lm) * 32 + ach * 8);
#pragma unroll
        for (int j = 0; j < 2; j++) {
          half8 b = *(const half8*)(Bs1 + (wn * 32 + j * 16 + lm) * 32 + ach * 8);
#pragma unroll
          for (int i = 0; i < 4; i++)
            acc[i][j] = __builtin_amdgcn_mfma_f32_16x16x32_f16(a[i], b, acc[i][j], 0, 0, 0);
        }
      }
    }
  }
  // epilogue: C/D layout col = lane&15, row = (lane>>4)*4 + reg
  int cn = lane & 15, rq = lane >> 4;
  float rs = rsqrtf(1.f + 1e-5f);
#pragma unroll
  for (int i = 0; i < 4; i++) {
#pragma unroll
    for (int r = 0; r < 4; r++) {
      int row = m0 + wm * 64 + i * 16 + rq * 4 + r;
      if (row < M) {
        int c = (row >> lshift) & 31;  // m = (bb*32+c)*L + j
        float scale = bng[c] * rs;
        float bias = bnb[c];
#pragma unroll
        for (int j = 0; j < 2; j++) {
          int col = n0 + wn * 32 + j * 16 + cn;
          if (col < NN) {
            size_t o = (size_t)row * NN + col;
            Out[o] = (acc[i][j][r] + Cin[o]) * scale + bias;
          }
        }
      }
    }
  }
}

// ROUND 27 wide (128x128, M>=8192): BK=64 spill-proofed, VERIFIED 122.8-125us,
// no spill. Unchanged.
__global__ __launch_bounds__(256, 3) void mfma_gcn_wide(PassSet s,
    const float* __restrict__ Cin, float* __restrict__ Out, int M,
    const float* __restrict__ bng, const float* __restrict__ bnb, int lshift) {
  __shared__ f16 As0[128 * 32];
  __shared__ f16 As1[128 * 32];
  __shared__ f16 Bs0[128 * 32];
  __shared__ f16 Bs1[128 * 32];
  int tid = threadIdx.x;
  int wave = tid >> 6, lane = tid & 63;
  int wm = wave >> 1, wn = wave & 1;
  int m0 = blockIdx.x * 128;
  int n0 = blockIdx.y * 128;
  int lm = lane & 15, kq = lane >> 4;  // frag: row lm, k-quad kq (8 k)
  int srow = tid >> 2, sc = tid & 3;
  int ar0 = m0 + srow;      if (ar0 > M - 1) ar0 = M - 1;
  int ar1 = m0 + srow + 64; if (ar1 > M - 1) ar1 = M - 1;
  size_t ag0 = (size_t)ar0 * KP + sc * 8;
  size_t ag1 = (size_t)ar1 * KP + sc * 8;
  size_t bg0 = (size_t)(n0 + srow) * KP + sc * 8;
  size_t bg1 = (size_t)(n0 + srow + 64) * KP + sc * 8;  // <= 511 < 512 pad
  int sl0 = srow * 32 + ((sc ^ ((srow >> 1) & 3)) << 3);
  int sl1 = sl0 + 64 * 32;
  int ach = kq ^ ((lm >> 1) & 3);

  floatx4 acc[4][4];
#pragma unroll
  for (int i = 0; i < 4; i++)
#pragma unroll
    for (int j = 0; j < 4; j++) acc[i][j] = (floatx4){0.f, 0.f, 0.f, 0.f};

  // named scalars: paXY / pbXY, X = row-block (0: srow, 1: srow+64),
  // Y = sub-strip (0: k0, 1: k0+32)
  float4 pa00, pa01, pa10, pa11, pb00, pb01, pb10, pb11;
  {
    const f16* Ap = s.A[0];
    const f16* Bp = s.B[0];
    pa00 = *(const float4*)(Ap + ag0);
    pa01 = *(const float4*)(Ap + ag0 + 32);
    pa10 = *(const float4*)(Ap + ag1);
    pa11 = *(const float4*)(Ap + ag1 + 32);
    pb00 = *(const float4*)(Bp + bg0);
    pb01 = *(const float4*)(Bp + bg0 + 32);
    pb10 = *(const float4*)(Bp + bg1);
    pb11 = *(const float4*)(Bp + bg1 + 32);
  }
#pragma unroll
  for (int p = 0; p < 10; p++) {
    const f16* __restrict__ Ap = s.A[p];
    const f16* __restrict__ Bp = s.B[p];
    const f16* __restrict__ Apn = s.A[p < 9 ? p + 1 : p];
    const f16* __restrict__ Bpn = s.B[p < 9 ? p + 1 : p];
    for (int k0 = 0; k0 < KP; k0 += 64) {
      __syncthreads();  // prior compute done reading LDS
      *(float4*)(As0 + sl0) = pa00;
      *(float4*)(As1 + sl0) = pa01;
      *(float4*)(As0 + sl1) = pa10;
      *(float4*)(As1 + sl1) = pa11;
      *(float4*)(Bs0 + sl0) = pb00;
      *(float4*)(Bs1 + sl0) = pb01;
      *(float4*)(Bs0 + sl1) = pb10;
      *(float4*)(Bs1 + sl1) = pb11;
      __syncthreads();  // staging visible
      {  // prefetch next round (2 sub-strips); latency overlaps compute
        bool lastk = (k0 == KP - 64);
        const f16* An = lastk ? Apn : Ap;
        const f16* Bn = lastk ? Bpn : Bp;
        int kn = lastk ? 0 : k0 + 64;
        pa00 = *(const float4*)(An + ag0 + kn);
        pa01 = *(const float4*)(An + ag0 + kn + 32);
        pa10 = *(const float4*)(An + ag1 + kn);
        pa11 = *(const float4*)(An + ag1 + kn + 32);
        pb00 = *(const float4*)(Bn + bg0 + kn);
        pb01 = *(const float4*)(Bn + bg0 + kn + 32);
        pb10 = *(const float4*)(Bn + bg1 + kn);
        pb11 = *(const float4*)(Bn + bg1 + kn + 32);
      }
      {  // sub-strip 0 (k0)
        half8 a[4];
#pragma unroll
        for (int i = 0; i < 4; i++)
          a[i] = *(const half8*)(As0 + (wm * 64 + i * 16 + lm) * 32 + ach * 8);
#pragma unroll
        for (int j = 0; j < 4; j++) {
          half8 b = *(const half8*)(Bs0 + (wn * 64 + j * 16 + lm) * 32 + ach * 8);
#pragma unroll
          for (int i = 0; i < 4; i++)
            acc[i][j] = __builtin_amdgcn_mfma_f32_16x16x32_f16(a[i], b, acc[i][j], 0, 0, 0);
        }
      }
      {  // sub-strip 1 (k0+32)
        half8 a[4];
#pragma unroll
        for (int i = 0; i < 4; i++)
          a[i] = *(const half8*)(As1 + (wm * 64 + i * 16 + lm) * 32 + ach * 8);
#pragma unroll
        for (int j = 0; j < 4; j++) {
          half8 b = *(const half8*)(Bs1 + (wn * 64 + j * 16 + lm) * 32 + ach * 8);
#pragma unroll
          for (int i = 0; i < 4; i++)
            acc[i][j] = __builtin_amdgcn_mfma_f32_16x16x32_f16(a[i], b, acc[i][j], 0, 0, 0);
        }
      }
    }
  }
  int cn = lane & 15, rq = lane >> 4;
  float rs = rsqrtf(1.f + 1e-5f);
#pragma unroll
  for (int i = 0; i < 4; i++) {
#pragma unroll
    for (int r = 0; r < 4; r++) {
      int row = m0 + wm * 64 + i * 16 + rq * 4 + r;
      if (row < M) {
        int c = (row >> lshift) & 31;  // m = (bb*32+c)*L + j
        float scale = bng[c] * rs;
        float bias = bnb[c];
#pragma unroll
        for (int j = 0; j < 4; j++) {
          int col = n0 + wn * 64 + j * 16 + cn;
          if (col < NN) {
            size_t o = (size_t)row * NN + col;
            Out[o] = (acc[i][j][r] + Cin[o]) * scale + bias;
          }
        }
      }
    }
  }
}

// ---------------------------------------------------------------------------
// skip -> relu -> end1 -> relu -> end2. One block per (b, 20 n-values).
#define NB 20
#define NBP 21
__global__ __launch_bounds__(256) void final_kernel(const float* __restrict__ tap,
    const float* __restrict__ skw, const float* __restrict__ skb,
    const float* __restrict__ e1w, const float* __restrict__ e1b,
    const float* __restrict__ e2w, const float* __restrict__ e2b,
    float* __restrict__ out) {
  __shared__ float tapS[256][NBP];
  __shared__ float skS[256][NBP];
  __shared__ float e1S[512][NBP];
  int tid = threadIdx.x;
  int b = blockIdx.y;
  int n0 = blockIdx.x * NB;
  {
    int i = tid >> 5, c = tid & 31;
    const float* tp = tap + (((size_t)i * 8 + b) * 32 + c) * NN + n0;
#pragma unroll
    for (int v = 0; v < NB; v++) tapS[tid][v] = tp[v];
  }
  __syncthreads();
  {
    float bsum = 0.f;
#pragma unroll
    for (int i2 = 0; i2 < 8; i2++) bsum += skb[i2 * 256 + tid];
    float acc[NB];
#pragma unroll
    for (int v = 0; v < NB; v++) acc[v] = bsum;
#pragma unroll
    for (int i2 = 0; i2 < 8; i2++) {
      const float* wr = skw + ((size_t)i2 * 256 + tid) * 32;
#pragma unroll
      for (int cp = 0; cp < 32; cp++) {
        float w = wr[cp];
#pragma unroll
        for (int v = 0; v < NB; v++) acc[v] = fmaf(w, tapS[i2 * 32 + cp][v], acc[v]);
      }
    }
#pragma unroll
    for (int v = 0; v < NB; v++) skS[tid][v] = fmaxf(acc[v], 0.f);
  }
  __syncthreads();
#pragma unroll
  for (int h = 0; h < 2; h++) {
    int k = tid + h * 256;
    float bv = e1b[k];
    float acc[NB];
#pragma unroll
    for (int v = 0; v < NB; v++) acc[v] = bv;
    const float* wr = e1w + (size_t)k * 256;
    for (int o = 0; o < 256; o++) {
      float w = wr[o];
#pragma unroll
      for (int v = 0; v < NB; v++) acc[v] = fmaf(w, skS[o][v], acc[v]);
    }
#pragma unroll
    for (int v = 0; v < NB; v++) e1S[k][v] = fmaxf(acc[v], 0.f);
  }
  __syncthreads();
  if (tid < 12 * NB) {
    int q = tid / NB, v = tid % NB;
    float acc = e2b[q];
    const float* wr = e2w + (size_t)q * 512;
#pragma unroll 8
    for (int k = 0; k < 512; k++) acc = fmaf(wr[k], e1S[k][v], acc);
    out[((size_t)b * 12 + q) * NN + n0 + v] = acc;
  }
}

// ---------------------------------------------------------------------------
extern "C" void kernel_launch(void* const* d_in, const int* in_sizes, int n_in,
                              void* d_out, int out_size, void* d_ws, size_t ws_size,
                              hipStream_t stream) {
  const float* x       = (const float*)d_in[0];
  const float* A0      = (const float*)d_in[1];
  const float* start_w = (const float*)d_in[2];
  const float* start_b = (const float*)d_in[3];
  const float* filt_w  = (const float*)d_in[4];
  const float* filt_b  = (const float*)d_in[5];
  const float* gate_w  = (const float*)d_in[6];
  const float* gate_b  = (const float*)d_in[7];
  const float* skip_w  = (const float*)d_in[8];
  const float* skip_b  = (const float*)d_in[9];
  const float* gcn_w   = (const float*)d_in[10];
  const float* gcn_b   = (const float*)d_in[11];
  const float* bn_g    = (const float*)d_in[12];
  const float* bn_b    = (const float*)d_in[13];
  const float* nv1     = (const float*)d_in[14];
  const float* nv2     = (const float*)d_in[15];
  const float* e1w     = (const float*)d_in[16];
  const float* e1b     = (const float*)d_in[17];
  const float* e2w     = (const float*)d_in[18];
  const float* e2b     = (const float*)d_in[19];
  float* out = (float*)d_out;

  char* ws = (char*)d_ws;
  size_t off = 0;
  auto alloc = [&](size_t bytes) -> void* {
    void* p = (void*)(ws + off);
    off += (bytes + 255) & ~(size_t)255;
    return p;
  };
  float* adp   = (float*)alloc((size_t)NN * NN * 4);
  float* tap   = (float*)alloc((size_t)8 * 8 * 32 * NN * 4);
  float* xT    = (float*)alloc((size_t)16 * 256 * NN * 4);  // [b*2+ch][t][n]
  float* fwT   = (float*)alloc((size_t)16384 * 4);  // dconv weights [i][cp][tap][c]
  float* gwT   = (float*)alloc((size_t)16384 * 4);
  f16*   A0tH  = (f16*)alloc((size_t)KP * KP * 2);
  f16*   A0tL  = (f16*)alloc((size_t)KP * KP * 2);
  f16*   adptH = (f16*)alloc((size_t)KP * KP * 2);
  f16*   adptL = (f16*)alloc((size_t)KP * KP * 2);
  f16*   Q0H   = (f16*)alloc((size_t)KP * KP * 2);   // (A0^2)^T pair
  f16*   Q0L   = (f16*)alloc((size_t)KP * KP * 2);
  f16*   QdH   = (f16*)alloc((size_t)KP * KP * 2);   // (adp^2)^T pair
  f16*   QdL   = (f16*)alloc((size_t)KP * KP * 2);
  size_t fixed = off;

  // Workspace ladder: pick batch-group g and rows-per-batch slab capacity rpb.
  // Layer i (rows/batch = 32*L_i) runs in nCh = ceil(32*L_i/rpb) bb-chunks
  // (pointer offsets only, bit-identical math).
  int g = 1, rpb = 512;
  {
    const int gcand[4] = {8, 4, 2, 1};
    const int rcand[4] = {4096, 2048, 1024, 512};
    bool found = false;
    for (int gi = 0; gi < 4 && !found; gi++) {
      for (int ri = 0; ri < 4 && !found; ri++) {
        int gg = gcand[gi], rr = rcand[ri];
        if (4096 / rr > gg) continue;  // layer-0 chunk count must be <= g
        size_t need = fixed + (size_t)gg * 12288000ull +
                      6ull * gg * rr * KP * 2 + (1u << 20);
        if (need <= ws_size) { g = gg; rpb = rr; found = true; }
      }
    }
  }
  float* h128 = (float*)alloc((size_t)g * 8192000ull);
  float* h64  = (float*)alloc((size_t)g * 4096000ull);
  int R = g * rpb;  // slab rows per f16 array
  f16* slab   = (f16*)alloc(6ull * R * KP * 2);
  f16* P1a  = slab + 0ull * R * KP;
  f16* P2aH = slab + 1ull * R * KP;
  f16* P2aL = slab + 2ull * R * KP;
  f16* P1b  = slab + 3ull * R * KP;
  f16* P2bH = slab + 4ull * R * KP;
  f16* P2bL = slab + 5ull * R * KP;

  adp_kernel<<<NN, 256, 0, stream>>>(nv1, nv2, adp);
  xt_kernel<<<dim3(16, 8, 16), 256, 0, stream>>>(x, xT);
  wtr_kernel<<<64, 256, 0, stream>>>(filt_w, gate_w, fwT, gwT);
  bt_kernel<<<1024, 256, 0, stream>>>(A0, A0tH, A0tL);
  bt_kernel<<<1024, 256, 0, stream>>>(adp, adptH, adptL);
  sq_kernel<<<dim3(512, 2), 512, 0, stream>>>(A0, adp, Q0H, Q0L, QdH, QdL);
  padzero_kernel<<<(36 * R + 255) / 256, 256, 0, stream>>>((uint32_t*)slab, R);

  // out = H + P1a*A0 + P2a*A0^2 + P1b*adp + P2b*adp^2; P2 terms as hi/lo
  // pairs (3 passes, lo*lo dropped), P1 terms single-f16 (2 passes).
  PassSet ps{};
  {
    const f16* Alist[10] = {P1a, P1a, P2aH, P2aH, P2aL, P1b, P1b, P2bH, P2bH, P2bL};
    const f16* Blist[10] = {A0tH, A0tL, Q0H, Q0L, Q0H, adptH, adptL, QdH, QdL, QdH};
    for (int q = 0; q < 10; q++) { ps.A[q] = Alist[q]; ps.B[q] = Blist[q]; }
  }

  for (int b0 = 0; b0 < 8; b0 += g) {
    float* hprev = nullptr;
    int Lp = 256;
    for (int i = 0; i < 8; i++) {
      int L = Lp >> 1;  // 128,64,...,1
      if (i < 7) {
        float* hout = (i & 1) ? h64 : h128;
        int rows = 32 * L;                       // per batch element
        int nCh = (rows + rpb - 1) / rpb;        // bb-chunks (<= g, power of 2)
        if (nCh < 1) nCh = 1;
        int bbw = g / nCh;
        for (int ch = 0; ch < nCh; ch++) {
          int bb0 = ch * bbw;
          const float* hprev_c = hprev ? hprev + (size_t)bb0 * 32 * Lp * NN : nullptr;
          float* hout_c = hout + (size_t)bb0 * 32 * L * NN;
          if (i == 0) {
            dcm_kernel<true><<<dim3(L, bbw, 2), 256, 0, stream>>>(
                nullptr, xT, start_w, start_b,
                fwT + i * 2048, filt_b + i * 32, gwT + i * 2048, gate_b + i * 32,
                gcn_w + i * 5120, gcn_b + i * 32, hout_c,
                P1a, P2aH, P2aL, P1b, P2bH, P2bL,
                tap + (size_t)i * 8 * 32 * NN, Lp, L, b0 + bb0);
          } else {
            dcm_kernel<false><<<dim3(L, bbw, 2), 256, 0, stream>>>(
                hprev_c, nullptr, nullptr, nullptr,
                fwT + i * 2048, filt_b + i * 32, gwT + i * 2048, gate_b + i * 32,
                gcn_w + i * 5120, gcn_b + i * 32, hout_c,
                P1a, P2aH, P2aL, P1b, P2bH, P2bL,
                tap + (size_t)i * 8 * 32 * NN, Lp, L, b0 + bb0);
          }
          int M = bbw * 32 * L;
          int Mb = (M + 127) / 128;
          if (M >= 8192) {
            mfma_gcn_wide<<<dim3(Mb, 4), 256, 0, stream>>>(ps, hout_c, hout_c, M,
                                                           bn_g + i * 32, bn_b + i * 32, 7 - i);
          } else {
            mfma_gcn<<<dim3(Mb, 8), 256, 0, stream>>>(ps, hout_c, hout_c, M,
                                                      bn_g + i * 32, bn_b + i * 32, 7 - i);
          }
        }
        hprev = hout;
        Lp = L;
      } else {
        // layer 8: only the skip tap survives
        dcm_kernel<false><<<dim3(1, g, 2), 256, 0, stream>>>(
            hprev, nullptr, nullptr, nullptr,
            fwT + i * 2048, filt_b + i * 32, gwT + i * 2048, gate_b + i * 32,
            gcn_w, gcn_b, nullptr,
            P1a, P2aH, P2aL, P1b, P2bH, P2bL,
            tap + (size_t)i * 8 * 32 * NN, Lp, 1, b0);
      }
    }
  }
  final_kernel<<<dim3(25, 8), 256, 0, stream>>>(tap, skip_w, skip_b, e1w, e1b, e2w, e2b, out);
}